// Round 1
// baseline (3682.045 us; speedup 1.0000x reference)
//
#include <hip/hip_runtime.h>
#include <cstddef>

// ---------------------------------------------------------------------------
// MegNet block, fp32 VALU implementation (round 0: correctness + baseline).
// E=800000 edges, N=100000 nodes, D=64, H=128. All fp32.
// ---------------------------------------------------------------------------

__device__ __forceinline__ float sp(float x) {
    // stable softplus = max(x,0) + log1p(exp(-|x|))
    return fmaxf(x, 0.f) + log1pf(__expf(-fabsf(x)));
}

#define FMA8(A, xx)                                                            \
    A[0] += (xx) * w0.x; A[1] += (xx) * w0.y; A[2] += (xx) * w0.z;             \
    A[3] += (xx) * w0.w; A[4] += (xx) * w1.x; A[5] += (xx) * w1.y;             \
    A[6] += (xx) * w1.z; A[7] += (xx) * w1.w;

// ---------------- pre-dense node MLP: v = softplus(nf @ W + b) -------------
__global__ __launch_bounds__(256) void pre_node_kernel(
    const float* __restrict__ nf, const float* __restrict__ W,
    const float* __restrict__ b, float* __restrict__ v, int N)
{
    __shared__ float X[32][68];
    const int t = threadIdx.x;
    const int n0 = blockIdx.x * 32;
#pragma unroll
    for (int r = 0; r < 2; ++r) {
        int flat = t + 256 * r;          // 0..511
        int e = flat >> 4, q = flat & 15;
        *(float4*)&X[e][4 * q] = *(const float4*)(nf + (size_t)(n0 + e) * 64 + 4 * q);
    }
    __syncthreads();
    const int e = t >> 3, j0 = (t & 7) * 8;
    float acc[8];
#pragma unroll
    for (int j = 0; j < 8; ++j) acc[j] = b[j0 + j];
    for (int k = 0; k < 64; ++k) {
        float x = X[e][k];
        const float* wr = W + k * 64 + j0;
        float4 w0 = *(const float4*)wr, w1 = *(const float4*)(wr + 4);
        FMA8(acc, x)
    }
    float* vo = v + (size_t)(n0 + e) * 64 + j0;
    float4 o0 = make_float4(sp(acc[0]), sp(acc[1]), sp(acc[2]), sp(acc[3]));
    float4 o1 = make_float4(sp(acc[4]), sp(acc[5]), sp(acc[6]), sp(acc[7]));
    *(float4*)vo = o0;
    *(float4*)(vo + 4) = o1;
}

// -------- pre-dense attr + fold u into edge/node layer-0 biases ------------
__global__ void pre_attr_kernel(
    const float* __restrict__ ga, const float* __restrict__ Wpa, const float* __restrict__ bpa,
    const float* __restrict__ eW0, const float* __restrict__ eb0,
    const float* __restrict__ nW0, const float* __restrict__ nb0,
    float* __restrict__ u, float* __restrict__ c0e, float* __restrict__ c0n)
{
    __shared__ float us[64];
    const int t = threadIdx.x;
    if (t < 64) {
        float acc = bpa[t];
        for (int k = 0; k < 64; ++k) acc += ga[k] * Wpa[k * 64 + t];
        float uu = sp(acc);
        us[t] = uu;
        u[t] = uu;
    }
    __syncthreads();
    if (t < 128) {
        float acc = eb0[t];
        for (int k = 0; k < 64; ++k) acc += us[k] * eW0[(192 + k) * 128 + t];
        c0e[t] = acc;
        float accn = nb0[t];
        for (int k = 0; k < 64; ++k) accn += us[k] * nW0[(128 + k) * 128 + t];
        c0n[t] = accn;
    }
}

// ---------------- incoming-edge counts per node ----------------------------
__global__ __launch_bounds__(256) void cnt_kernel(
    const int* __restrict__ dst, int* __restrict__ cnt, int E)
{
    int i = blockIdx.x * 256 + threadIdx.x;
    if (i < E) atomicAdd(&cnt[dst[i]], 1);
}

// ---------------- edge kernel: 32 edges per block --------------------------
__global__ __launch_bounds__(256) void edge_kernel(
    const float* __restrict__ ef, const float* __restrict__ v,
    const int* __restrict__ src, const int* __restrict__ dst,
    const float* __restrict__ Wpe, const float* __restrict__ bpe,
    const float* __restrict__ W0, const float* __restrict__ W1, const float* __restrict__ b1,
    const float* __restrict__ W2, const float* __restrict__ b2,
    const float* __restrict__ c0e,
    float* __restrict__ e_out, float* __restrict__ sumE)
{
    __shared__ float X[32][200];   // layer inputs: [vsrc | vdst | e_pre] then h1
    __shared__ float Hs[32][132];  // h0
    __shared__ float EF[32][68];   // original edge features (for pre-dense + skip)
    const int t = threadIdx.x;
    const int e0 = blockIdx.x * 32;

#pragma unroll
    for (int r = 0; r < 2; ++r) {
        int flat = t + 256 * r;
        int e = flat >> 4, q = flat & 15;
        *(float4*)&EF[e][4 * q] = *(const float4*)(ef + (size_t)(e0 + e) * 64 + 4 * q);
    }
#pragma unroll
    for (int r = 0; r < 4; ++r) {
        int flat = t + 256 * r;          // 0..1023
        int e = flat >> 5, s = flat & 31;
        int node = (s < 16) ? src[e0 + e] : dst[e0 + e];
        int q = s & 15;
        *(float4*)&X[e][(s < 16 ? 0 : 64) + 4 * q] =
            *(const float4*)(v + (size_t)node * 64 + 4 * q);
    }
    __syncthreads();

    // pre-dense edge: X[:,128:192] = softplus(EF @ Wpe + bpe)
    {
        const int e = t >> 3, j0 = (t & 7) * 8;
        float acc[8];
#pragma unroll
        for (int j = 0; j < 8; ++j) acc[j] = bpe[j0 + j];
        for (int k = 0; k < 64; ++k) {
            float x = EF[e][k];
            const float* wr = Wpe + k * 64 + j0;
            float4 w0 = *(const float4*)wr, w1 = *(const float4*)(wr + 4);
            FMA8(acc, x)
        }
#pragma unroll
        for (int j = 0; j < 8; ++j) X[e][128 + j0 + j] = sp(acc[j]);
    }
    __syncthreads();

    // layer0: X[32][192] @ W0[192][128] + c0e -> Hs
    {
        const int ea = (t >> 4) * 2, eb = ea + 1, j0 = (t & 15) * 8;
        float a0[8], a1[8];
#pragma unroll
        for (int j = 0; j < 8; ++j) { float c = c0e[j0 + j]; a0[j] = c; a1[j] = c; }
        for (int k = 0; k < 192; ++k) {
            float xa = X[ea][k], xb = X[eb][k];
            const float* wr = W0 + k * 128 + j0;
            float4 w0 = *(const float4*)wr, w1 = *(const float4*)(wr + 4);
            FMA8(a0, xa)
            FMA8(a1, xb)
        }
#pragma unroll
        for (int j = 0; j < 8; ++j) { Hs[ea][j0 + j] = sp(a0[j]); Hs[eb][j0 + j] = sp(a1[j]); }
    }
    __syncthreads();

    // layer1: Hs[32][128] @ W1[128][128] + b1 -> X[:,0:128]
    {
        const int ea = (t >> 4) * 2, eb = ea + 1, j0 = (t & 15) * 8;
        float a0[8], a1[8];
#pragma unroll
        for (int j = 0; j < 8; ++j) { float c = b1[j0 + j]; a0[j] = c; a1[j] = c; }
        for (int k = 0; k < 128; ++k) {
            float xa = Hs[ea][k], xb = Hs[eb][k];
            const float* wr = W1 + k * 128 + j0;
            float4 w0 = *(const float4*)wr, w1 = *(const float4*)(wr + 4);
            FMA8(a0, xa)
            FMA8(a1, xb)
        }
#pragma unroll
        for (int j = 0; j < 8; ++j) { X[ea][j0 + j] = sp(a0[j]); X[eb][j0 + j] = sp(a1[j]); }
    }
    __syncthreads();

    // layer2: X[32][128] @ W2[128][64] + b2 -> e_new; skip add + segment sum
    {
        const int e = t >> 3, j0 = (t & 7) * 8;
        float acc[8];
#pragma unroll
        for (int j = 0; j < 8; ++j) acc[j] = b2[j0 + j];
        for (int k = 0; k < 128; ++k) {
            float x = X[e][k];
            const float* wr = W2 + k * 64 + j0;
            float4 w0 = *(const float4*)wr, w1 = *(const float4*)(wr + 4);
            FMA8(acc, x)
        }
        float en[8];
#pragma unroll
        for (int j = 0; j < 8; ++j) en[j] = sp(acc[j]);
        const int ge = e0 + e;
        float4 o0 = make_float4(en[0] + EF[e][j0 + 0], en[1] + EF[e][j0 + 1],
                                en[2] + EF[e][j0 + 2], en[3] + EF[e][j0 + 3]);
        float4 o1 = make_float4(en[4] + EF[e][j0 + 4], en[5] + EF[e][j0 + 5],
                                en[6] + EF[e][j0 + 6], en[7] + EF[e][j0 + 7]);
        float* eo = e_out + (size_t)ge * 64 + j0;
        *(float4*)eo = o0;
        *(float4*)(eo + 4) = o1;
        const int d = dst[ge];
        float* se = sumE + (size_t)d * 64 + j0;
#pragma unroll
        for (int j = 0; j < 8; ++j) atomicAdd(se + j, en[j]);
    }
}

// ---------------- node kernel: 32 nodes per block --------------------------
__global__ __launch_bounds__(256) void node_kernel(
    const float* __restrict__ nf, const float* __restrict__ v,
    const int* __restrict__ cnt,
    const float* __restrict__ W0, const float* __restrict__ W1, const float* __restrict__ b1,
    const float* __restrict__ W2, const float* __restrict__ b2,
    const float* __restrict__ c0n,
    float* __restrict__ vio,   // in: sumE ; out: v_new + nf (same buffer)
    float* __restrict__ acc_e, float* __restrict__ acc_v)
{
    __shared__ float X[32][200];
    __shared__ float Hs[32][132];
    const int t = threadIdx.x;
    const int n0 = blockIdx.x * 32;

#pragma unroll
    for (int r = 0; r < 2; ++r) {
        int flat = t + 256 * r;
        int e = flat >> 4, q = flat & 15;
        *(float4*)&X[e][4 * q] = *(const float4*)(v + (size_t)(n0 + e) * 64 + 4 * q);
    }
#pragma unroll
    for (int r = 0; r < 2; ++r) {
        int flat = t + 256 * r;
        int e = flat >> 4, q = flat & 15;
        int n = n0 + e;
        float4 s4 = *(const float4*)(vio + (size_t)n * 64 + 4 * q);
        *(float4*)&Hs[e][4 * q] = s4;   // raw segment sums, for ue readout
        float rc = 1.f / fmaxf((float)cnt[n], 1.f);
        float4 ve = make_float4(s4.x * rc, s4.y * rc, s4.z * rc, s4.w * rc);
        *(float4*)&X[e][64 + 4 * q] = ve;
    }
    __syncthreads();
    if (t < 64) {
        float s = 0.f;
#pragma unroll
        for (int e = 0; e < 32; ++e) s += Hs[e][t];
        atomicAdd(acc_e + t, s);
    }
    __syncthreads();

    // layer0: X[32][128] @ W0[rows 0..127][128] + c0n -> Hs
    {
        const int ea = (t >> 4) * 2, eb = ea + 1, j0 = (t & 15) * 8;
        float a0[8], a1[8];
#pragma unroll
        for (int j = 0; j < 8; ++j) { float c = c0n[j0 + j]; a0[j] = c; a1[j] = c; }
        for (int k = 0; k < 128; ++k) {
            float xa = X[ea][k], xb = X[eb][k];
            const float* wr = W0 + k * 128 + j0;
            float4 w0 = *(const float4*)wr, w1 = *(const float4*)(wr + 4);
            FMA8(a0, xa)
            FMA8(a1, xb)
        }
#pragma unroll
        for (int j = 0; j < 8; ++j) { Hs[ea][j0 + j] = sp(a0[j]); Hs[eb][j0 + j] = sp(a1[j]); }
    }
    __syncthreads();

    // layer1: Hs @ W1 + b1 -> X[:,0:128]
    {
        const int ea = (t >> 4) * 2, eb = ea + 1, j0 = (t & 15) * 8;
        float a0[8], a1[8];
#pragma unroll
        for (int j = 0; j < 8; ++j) { float c = b1[j0 + j]; a0[j] = c; a1[j] = c; }
        for (int k = 0; k < 128; ++k) {
            float xa = Hs[ea][k], xb = Hs[eb][k];
            const float* wr = W1 + k * 128 + j0;
            float4 w0 = *(const float4*)wr, w1 = *(const float4*)(wr + 4);
            FMA8(a0, xa)
            FMA8(a1, xb)
        }
#pragma unroll
        for (int j = 0; j < 8; ++j) { X[ea][j0 + j] = sp(a0[j]); X[eb][j0 + j] = sp(a1[j]); }
    }
    __syncthreads();

    // layer2: X[:,0:128] @ W2[128][64] + b2 -> v_new; skip + uv readout
    {
        const int e = t >> 3, j0 = (t & 7) * 8;
        float acc[8];
#pragma unroll
        for (int j = 0; j < 8; ++j) acc[j] = b2[j0 + j];
        for (int k = 0; k < 128; ++k) {
            float x = X[e][k];
            const float* wr = W2 + k * 64 + j0;
            float4 w0 = *(const float4*)wr, w1 = *(const float4*)(wr + 4);
            FMA8(acc, x)
        }
        float vn[8];
#pragma unroll
        for (int j = 0; j < 8; ++j) vn[j] = sp(acc[j]);
        const int n = n0 + e;
        const float* nfr = nf + (size_t)n * 64 + j0;
        float4 i0 = *(const float4*)nfr, i1 = *(const float4*)(nfr + 4);
        float4 o0 = make_float4(vn[0] + i0.x, vn[1] + i0.y, vn[2] + i0.z, vn[3] + i0.w);
        float4 o1 = make_float4(vn[4] + i1.x, vn[5] + i1.y, vn[6] + i1.z, vn[7] + i1.w);
        float* vo = vio + (size_t)n * 64 + j0;
        *(float4*)vo = o0;
        *(float4*)(vo + 4) = o1;
#pragma unroll
        for (int j = 0; j < 8; ++j) Hs[e][j0 + j] = vn[j];  // raw v_new for uv
    }
    __syncthreads();
    if (t < 64) {
        float s = 0.f;
#pragma unroll
        for (int e = 0; e < 32; ++e) s += Hs[e][t];
        atomicAdd(acc_v + t, s);
    }
}

// ---------------- attr kernel: single block --------------------------------
__global__ void attr_kernel(
    const float* __restrict__ ga, const float* __restrict__ u,
    const float* __restrict__ acc_e, const float* __restrict__ acc_v,
    const float* __restrict__ W0, const float* __restrict__ b0,
    const float* __restrict__ W1, const float* __restrict__ b1,
    const float* __restrict__ W2, const float* __restrict__ b2,
    float* __restrict__ out_u, float Einv, float Ninv)
{
    __shared__ float ain[192];
    __shared__ float h0[128];
    __shared__ float h1[128];
    const int t = threadIdx.x;
    if (t < 64) {
        ain[t] = u[t];
        ain[64 + t] = acc_e[t] * Einv;
        ain[128 + t] = acc_v[t] * Ninv;
    }
    __syncthreads();
    if (t < 128) {
        float a = b0[t];
        for (int k = 0; k < 192; ++k) a += ain[k] * W0[k * 128 + t];
        h0[t] = sp(a);
    }
    __syncthreads();
    if (t < 128) {
        float a = b1[t];
        for (int k = 0; k < 128; ++k) a += h0[k] * W1[k * 128 + t];
        h1[t] = sp(a);
    }
    __syncthreads();
    if (t < 64) {
        float a = b2[t];
        for (int k = 0; k < 128; ++k) a += h1[k] * W2[k * 64 + t];
        out_u[t] = sp(a) + ga[t];
    }
}

// ---------------------------------------------------------------------------
extern "C" void kernel_launch(void* const* d_in, const int* in_sizes, int n_in,
                              void* d_out, int out_size, void* d_ws, size_t ws_size,
                              hipStream_t stream)
{
    const float* edge_feat = (const float*)d_in[0];
    const float* node_feat = (const float*)d_in[1];
    const float* graph_attr = (const float*)d_in[2];
    const int*   src = (const int*)d_in[3];
    const int*   dst = (const int*)d_in[4];
    const float* pre_edge_w = (const float*)d_in[5];
    const float* pre_edge_b = (const float*)d_in[6];
    const float* pre_node_w = (const float*)d_in[7];
    const float* pre_node_b = (const float*)d_in[8];
    const float* pre_attr_w = (const float*)d_in[9];
    const float* pre_attr_b = (const float*)d_in[10];
    const float* edge_w0 = (const float*)d_in[11];
    const float* edge_b0 = (const float*)d_in[12];
    const float* edge_w1 = (const float*)d_in[13];
    const float* edge_b1 = (const float*)d_in[14];
    const float* edge_w2 = (const float*)d_in[15];
    const float* edge_b2 = (const float*)d_in[16];
    const float* node_w0 = (const float*)d_in[17];
    const float* node_b0 = (const float*)d_in[18];
    const float* node_w1 = (const float*)d_in[19];
    const float* node_b1 = (const float*)d_in[20];
    const float* node_w2 = (const float*)d_in[21];
    const float* node_b2 = (const float*)d_in[22];
    const float* attr_w0 = (const float*)d_in[23];
    const float* attr_b0 = (const float*)d_in[24];
    const float* attr_w1 = (const float*)d_in[25];
    const float* attr_b1 = (const float*)d_in[26];
    const float* attr_w2 = (const float*)d_in[27];
    const float* attr_b2 = (const float*)d_in[28];

    const int E = in_sizes[0] / 64;
    const int N = in_sizes[1] / 64;

    // workspace layout
    float* ws = (float*)d_ws;
    float* v   = ws;                              // N*64 floats
    int*   cnt = (int*)(ws + (size_t)N * 64);     // N ints
    float* u   = (float*)(cnt + N);               // 64
    float* c0e = u + 64;                          // 128
    float* c0n = c0e + 128;                       // 128
    float* acc_e = c0n + 128;                     // 64
    float* acc_v = acc_e + 64;                    // 64

    float* e_out = (float*)d_out;                    // E*64
    float* sumE  = e_out + (size_t)E * 64;           // N*64 (sumE then v_out)
    float* u_out = sumE + (size_t)N * 64;            // 64

    // zero: cnt + u/c0e/c0n/accums, and sumE region of d_out
    hipMemsetAsync(cnt, 0, sizeof(int) * (size_t)N + sizeof(float) * (64 + 128 + 128 + 64 + 64), stream);
    hipMemsetAsync(sumE, 0, sizeof(float) * (size_t)N * 64, stream);

    pre_node_kernel<<<(N + 31) / 32, 256, 0, stream>>>(node_feat, pre_node_w, pre_node_b, v, N);
    pre_attr_kernel<<<1, 128, 0, stream>>>(graph_attr, pre_attr_w, pre_attr_b,
                                           edge_w0, edge_b0, node_w0, node_b0,
                                           u, c0e, c0n);
    cnt_kernel<<<(E + 255) / 256, 256, 0, stream>>>(dst, cnt, E);
    edge_kernel<<<(E + 31) / 32, 256, 0, stream>>>(
        edge_feat, v, src, dst, pre_edge_w, pre_edge_b,
        edge_w0, edge_w1, edge_b1, edge_w2, edge_b2, c0e, e_out, sumE);
    node_kernel<<<(N + 31) / 32, 256, 0, stream>>>(
        node_feat, v, cnt, node_w0, node_w1, node_b1, node_w2, node_b2, c0n,
        sumE, acc_e, acc_v);
    attr_kernel<<<1, 128, 0, stream>>>(
        graph_attr, u, acc_e, acc_v,
        attr_w0, attr_b0, attr_w1, attr_b1, attr_w2, attr_b2,
        u_out, 1.f / (float)E, 1.f / (float)N);
}

// Round 2
// 1141.789 us; speedup vs baseline: 3.2248x; 3.2248x over previous
//
#include <hip/hip_runtime.h>
#include <cstddef>

// ---------------------------------------------------------------------------
// MegNet block, round 1: bf16 MFMA for edge/node MLPs.
// E=800000, N=100000, D=64, H=128.
// ---------------------------------------------------------------------------

typedef __attribute__((ext_vector_type(8))) short short8;   // 8 bf16 (4 VGPRs)
typedef __attribute__((ext_vector_type(4))) float f32x4;
typedef __attribute__((ext_vector_type(4))) unsigned int u32x4;

__device__ __forceinline__ float sp(float x) {
    return fmaxf(x, 0.f) + log1pf(__expf(-fabsf(x)));
}
__device__ __forceinline__ unsigned short f2bf(float x) {
    unsigned int u = __float_as_uint(x);
    u += 0x7fff + ((u >> 16) & 1);          // RNE
    return (unsigned short)(u >> 16);
}
__device__ __forceinline__ unsigned int pk2(float lo, float hi) {
    return (unsigned int)f2bf(lo) | ((unsigned int)f2bf(hi) << 16);
}
__device__ __forceinline__ u32x4 pack8(f32x4 a, f32x4 b) {
    u32x4 r;
    r.x = pk2(a[0], a[1]); r.y = pk2(a[2], a[3]);
    r.z = pk2(b[0], b[1]); r.w = pk2(b[2], b[3]);
    return r;
}
// 16B-chunk XOR swizzle: byte offset for (row, chunk) in a tile of row stride S
__device__ __forceinline__ int swz(int row, int chunk, int stride) {
    return row * stride + 128 * (chunk >> 3) + 16 * ((chunk & 7) ^ (row & 7));
}
__device__ __forceinline__ f32x4 mfma16(short8 a, short8 b, f32x4 c) {
    return __builtin_amdgcn_mfma_f32_16x16x32_bf16(a, b, c, 0, 0, 0);
}

#define FMA8(A, xx)                                                            \
    A[0] += (xx) * w0.x; A[1] += (xx) * w0.y; A[2] += (xx) * w0.z;             \
    A[3] += (xx) * w0.w; A[4] += (xx) * w1.x; A[5] += (xx) * w1.y;             \
    A[6] += (xx) * w1.z; A[7] += (xx) * w1.w;

// ---------------- weight transpose+bf16 prep -------------------------------
// out layout (bf16, [N][K] row-major each):
//   WpeT @0 (64x64), We0T @4096 (128x192), We1T @28672 (128x128),
//   We2T @45056 (64x128), Wn0T @53248 (128x128), Wn1T @69632 (128x128),
//   Wn2T @86016 (64x128); total 94208 elems
__global__ __launch_bounds__(256) void wprep(
    const float* __restrict__ Wpe, const float* __restrict__ We0,
    const float* __restrict__ We1, const float* __restrict__ We2,
    const float* __restrict__ Wn0, const float* __restrict__ Wn1,
    const float* __restrict__ Wn2, unsigned short* __restrict__ out)
{
    int idx = blockIdx.x * 256 + threadIdx.x;
    const float* src; int K, N, base;
    if      (idx < 4096)  { src = Wpe; K = 64;  N = 64;  base = 0; }
    else if (idx < 28672) { src = We0; K = 192; N = 128; base = 4096; }
    else if (idx < 45056) { src = We1; K = 128; N = 128; base = 28672; }
    else if (idx < 53248) { src = We2; K = 128; N = 64;  base = 45056; }
    else if (idx < 69632) { src = Wn0; K = 128; N = 128; base = 53248; }
    else if (idx < 86016) { src = Wn1; K = 128; N = 128; base = 69632; }
    else if (idx < 94208) { src = Wn2; K = 128; N = 64;  base = 86016; }
    else return;
    int r = idx - base, n = r / K, k = r % K;
    out[idx] = f2bf(src[(size_t)k * N + n]);
}

// ---------------- pre-dense node MLP -> bf16 v -----------------------------
__global__ __launch_bounds__(256) void pre_node_kernel(
    const float* __restrict__ nf, const float* __restrict__ W,
    const float* __restrict__ b, unsigned short* __restrict__ vb, int N)
{
    __shared__ float X[32][68];
    const int t = threadIdx.x;
    const int n0 = blockIdx.x * 32;
#pragma unroll
    for (int r = 0; r < 2; ++r) {
        int flat = t + 256 * r;
        int e = flat >> 4, q = flat & 15;
        *(f32x4*)&X[e][4 * q] = *(const f32x4*)(nf + (size_t)(n0 + e) * 64 + 4 * q);
    }
    __syncthreads();
    const int e = t >> 3, j0 = (t & 7) * 8;
    float acc[8];
#pragma unroll
    for (int j = 0; j < 8; ++j) acc[j] = b[j0 + j];
    for (int k = 0; k < 64; ++k) {
        float x = X[e][k];
        const float* wr = W + k * 64 + j0;
        float4 w0 = *(const float4*)wr, w1 = *(const float4*)(wr + 4);
        FMA8(acc, x)
    }
    f32x4 A = {sp(acc[0]), sp(acc[1]), sp(acc[2]), sp(acc[3])};
    f32x4 B = {sp(acc[4]), sp(acc[5]), sp(acc[6]), sp(acc[7])};
    *(u32x4*)(vb + (size_t)(n0 + e) * 64 + j0) = pack8(A, B);
}

// -------- pre-dense attr + fold u into edge/node layer-0 biases ------------
__global__ void pre_attr_kernel(
    const float* __restrict__ ga, const float* __restrict__ Wpa, const float* __restrict__ bpa,
    const float* __restrict__ eW0, const float* __restrict__ eb0,
    const float* __restrict__ nW0, const float* __restrict__ nb0,
    float* __restrict__ u, float* __restrict__ c0e, float* __restrict__ c0n)
{
    __shared__ float us[64];
    const int t = threadIdx.x;
    if (t < 64) {
        float acc = bpa[t];
        for (int k = 0; k < 64; ++k) acc += ga[k] * Wpa[k * 64 + t];
        float uu = sp(acc);
        us[t] = uu;
        u[t] = uu;
    }
    __syncthreads();
    if (t < 128) {
        float acc = eb0[t];
        for (int k = 0; k < 64; ++k) acc += us[k] * eW0[(192 + k) * 128 + t];
        c0e[t] = acc;
        float accn = nb0[t];
        for (int k = 0; k < 64; ++k) accn += us[k] * nW0[(128 + k) * 128 + t];
        c0n[t] = accn;
    }
}

// ---------------- incoming-edge counts per node ----------------------------
__global__ __launch_bounds__(256) void cnt_kernel(
    const int* __restrict__ dst, int* __restrict__ cnt, int E)
{
    int i = blockIdx.x * 256 + threadIdx.x;
    if (i < E) atomicAdd(&cnt[dst[i]], 1);
}

// ---------------- edge kernel: 64 edges / block, 4 waves, MFMA -------------
// LDS: X [64][192] bf16 s384 @0 (24576) | EF [64][64] bf16 s128 @24576 (8192)
//      H0 [64][128] bf16 s256 @32768 (16384)  -> total 49152
// H1 reuses X region (s256); e_new f32 [64][64] s256 reuses H0 region.
#define ELDS_X  0
#define ELDS_EF 24576
#define ELDS_H  32768

__global__ __launch_bounds__(256, 3) void edge_kernel(
    const float* __restrict__ ef, const unsigned short* __restrict__ vb,
    const int* __restrict__ src, const int* __restrict__ dst,
    const unsigned short* __restrict__ WpeT, const float* __restrict__ bpe,
    const unsigned short* __restrict__ W0T, const float* __restrict__ c0e,
    const unsigned short* __restrict__ W1T, const float* __restrict__ b1,
    const unsigned short* __restrict__ W2T, const float* __restrict__ b2,
    float* __restrict__ e_out, float* __restrict__ sumE)
{
    __shared__ __align__(16) char lds[49152];
    const int t = threadIdx.x;
    const int w = t >> 6, l = t & 63;
    const int l15 = l & 15, l4 = l >> 4;
    const int e0 = blockIdx.x * 64;

    // phase 0a: edge features fp32 -> bf16 LDS
#pragma unroll
    for (int rr = 0; rr < 2; ++rr) {
        int f = t + 256 * rr;
        int e = f >> 3, c = f & 7;
        const float* p = ef + (size_t)(e0 + e) * 64 + c * 8;
        f32x4 x0 = *(const f32x4*)p, x1 = *(const f32x4*)(p + 4);
        *(u32x4*)(lds + ELDS_EF + swz(e, c, 128)) = pack8(x0, x1);
    }
    // phase 0b: gather v[src], v[dst] (bf16)
#pragma unroll
    for (int rr = 0; rr < 4; ++rr) {
        int f = t + 256 * rr;
        int e = f >> 4, c = f & 15;
        int node = (c < 8) ? src[e0 + e] : dst[e0 + e];
        u32x4 d = *(const u32x4*)(vb + (size_t)node * 64 + (c & 7) * 8);
        *(u32x4*)(lds + ELDS_X + swz(e, c, 384)) = d;
    }
    __syncthreads();

    // phase 1: pre-dense edge MLP (K=64, N=64) -> X cols 128..191
    {
        const int col = w * 16 + l15;
        short8 B[2];
#pragma unroll
        for (int ks = 0; ks < 2; ++ks)
            B[ks] = *(const short8*)(WpeT + col * 64 + ks * 32 + l4 * 8);
        float bb = bpe[col];
#pragma unroll
        for (int m = 0; m < 4; ++m) {
            f32x4 acc = {0.f, 0.f, 0.f, 0.f};
#pragma unroll
            for (int ks = 0; ks < 2; ++ks) {
                short8 a = *(const short8*)(lds + ELDS_EF + swz(m * 16 + l15, ks * 4 + l4, 128));
                acc = mfma16(a, B[ks], acc);
            }
#pragma unroll
            for (int r = 0; r < 4; ++r) {
                int row = m * 16 + l4 * 4 + r;
                int cc = 128 + col;
                *(unsigned short*)(lds + ELDS_X + swz(row, cc >> 3, 384) + (cc & 7) * 2) =
                    f2bf(sp(acc[r] + bb));
            }
        }
    }
    __syncthreads();

    // phase 2: layer0 (K=192, N=128) -> H0
    {
        short8 B[2][6];
#pragma unroll
        for (int n = 0; n < 2; ++n) {
            int col = w * 32 + n * 16 + l15;
#pragma unroll
            for (int ks = 0; ks < 6; ++ks)
                B[n][ks] = *(const short8*)(W0T + col * 192 + ks * 32 + l4 * 8);
        }
        float bb0 = c0e[w * 32 + l15], bb1 = c0e[w * 32 + 16 + l15];
#pragma unroll
        for (int m = 0; m < 4; ++m) {
            f32x4 a0 = {0.f, 0.f, 0.f, 0.f}, a1 = {0.f, 0.f, 0.f, 0.f};
#pragma unroll
            for (int ks = 0; ks < 6; ++ks) {
                short8 a = *(const short8*)(lds + ELDS_X + swz(m * 16 + l15, ks * 4 + l4, 384));
                a0 = mfma16(a, B[0][ks], a0);
                a1 = mfma16(a, B[1][ks], a1);
            }
#pragma unroll
            for (int r = 0; r < 4; ++r) {
                int row = m * 16 + l4 * 4 + r;
                int c0 = w * 32 + l15, c1 = c0 + 16;
                *(unsigned short*)(lds + ELDS_H + swz(row, c0 >> 3, 256) + (c0 & 7) * 2) = f2bf(sp(a0[r] + bb0));
                *(unsigned short*)(lds + ELDS_H + swz(row, c1 >> 3, 256) + (c1 & 7) * 2) = f2bf(sp(a1[r] + bb1));
            }
        }
    }
    __syncthreads();

    // phase 3: layer1 (K=128, N=128): H0 -> H1 (X region, s256)
    {
        short8 B[2][4];
#pragma unroll
        for (int n = 0; n < 2; ++n) {
            int col = w * 32 + n * 16 + l15;
#pragma unroll
            for (int ks = 0; ks < 4; ++ks)
                B[n][ks] = *(const short8*)(W1T + col * 128 + ks * 32 + l4 * 8);
        }
        float bb0 = b1[w * 32 + l15], bb1 = b1[w * 32 + 16 + l15];
#pragma unroll
        for (int m = 0; m < 4; ++m) {
            f32x4 a0 = {0.f, 0.f, 0.f, 0.f}, a1 = {0.f, 0.f, 0.f, 0.f};
#pragma unroll
            for (int ks = 0; ks < 4; ++ks) {
                short8 a = *(const short8*)(lds + ELDS_H + swz(m * 16 + l15, ks * 4 + l4, 256));
                a0 = mfma16(a, B[0][ks], a0);
                a1 = mfma16(a, B[1][ks], a1);
            }
#pragma unroll
            for (int r = 0; r < 4; ++r) {
                int row = m * 16 + l4 * 4 + r;
                int c0 = w * 32 + l15, c1 = c0 + 16;
                *(unsigned short*)(lds + ELDS_X + swz(row, c0 >> 3, 256) + (c0 & 7) * 2) = f2bf(sp(a0[r] + bb0));
                *(unsigned short*)(lds + ELDS_X + swz(row, c1 >> 3, 256) + (c1 & 7) * 2) = f2bf(sp(a1[r] + bb1));
            }
        }
    }
    __syncthreads();

    // phase 4: layer2 (K=128, N=64): H1 -> e_new (f32, H0 region)
    {
        const int col = w * 16 + l15;
        short8 B[4];
#pragma unroll
        for (int ks = 0; ks < 4; ++ks)
            B[ks] = *(const short8*)(W2T + col * 128 + ks * 32 + l4 * 8);
        float bb = b2[col];
#pragma unroll
        for (int m = 0; m < 4; ++m) {
            f32x4 acc = {0.f, 0.f, 0.f, 0.f};
#pragma unroll
            for (int ks = 0; ks < 4; ++ks) {
                short8 a = *(const short8*)(lds + ELDS_X + swz(m * 16 + l15, ks * 4 + l4, 256));
                acc = mfma16(a, B[ks], acc);
            }
#pragma unroll
            for (int r = 0; r < 4; ++r) {
                int row = m * 16 + l4 * 4 + r;
                *(float*)(lds + ELDS_H + swz(row, col >> 2, 256) + (col & 3) * 4) = sp(acc[r] + bb);
            }
        }
    }
    __syncthreads();

    // phase 5: epilogue — skip add, store, segment-sum atomics
#pragma unroll
    for (int rr = 0; rr < 4; ++rr) {
        int f = t + 256 * rr;
        int e = f >> 4, c = f & 15;
        f32x4 en = *(const f32x4*)(lds + ELDS_H + swz(e, c, 256));
        f32x4 ei = *(const f32x4*)(ef + (size_t)(e0 + e) * 64 + c * 4);
        f32x4 o = en + ei;
        *(f32x4*)(e_out + (size_t)(e0 + e) * 64 + c * 4) = o;
        int d = dst[e0 + e];
        float* sb = sumE + (size_t)d * 64 + c * 4;
        atomicAdd(sb + 0, en[0]); atomicAdd(sb + 1, en[1]);
        atomicAdd(sb + 2, en[2]); atomicAdd(sb + 3, en[3]);
    }
}

// ---------------- node kernel: 64 nodes / block, MFMA ----------------------
// LDS: Xn [64][128] bf16 s256 @0 (16384) | H [64][128] bf16 s256 @16384 (16384)
// H region first holds raw sums f32 [64][64] s256, later v_new f32.
// H1 reuses Xn region.
#define NLDS_X 0
#define NLDS_H 16384

__global__ __launch_bounds__(256, 3) void node_kernel(
    const float* __restrict__ nf, const unsigned short* __restrict__ vb,
    const int* __restrict__ cnt,
    const unsigned short* __restrict__ W0T, const float* __restrict__ c0n,
    const unsigned short* __restrict__ W1T, const float* __restrict__ b1,
    const unsigned short* __restrict__ W2T, const float* __restrict__ b2,
    float* vio, float* __restrict__ acc_e, float* __restrict__ acc_v, int N)
{
    __shared__ __align__(16) char lds[32768];
    const int t = threadIdx.x;
    const int w = t >> 6, l = t & 63;
    const int l15 = l & 15, l4 = l >> 4;
    const int n0 = blockIdx.x * 64;

    // phase 0a: v (bf16) rows
#pragma unroll
    for (int rr = 0; rr < 2; ++rr) {
        int f = t + 256 * rr;
        int e = f >> 3, c = f & 7;
        int n = n0 + e; if (n >= N) n = N - 1;
        u32x4 d = *(const u32x4*)(vb + (size_t)n * 64 + c * 8);
        *(u32x4*)(lds + NLDS_X + swz(e, c, 256)) = d;
    }
    // phase 0b: segment sums -> raw (f32, H region) + ve (bf16, Xn cols 64..127)
#pragma unroll
    for (int rr = 0; rr < 2; ++rr) {
        int f = t + 256 * rr;
        int e = f >> 3, c = f & 7;
        int n = n0 + e;
        bool valid = n < N;
        int ns = valid ? n : N - 1;
        const float* p = vio + (size_t)ns * 64 + c * 8;
        f32x4 s0 = *(const f32x4*)p, s1 = *(const f32x4*)(p + 4);
        f32x4 z = {0.f, 0.f, 0.f, 0.f};
        if (!valid) { s0 = z; s1 = z; }
        float rc = valid ? 1.f / fmaxf((float)cnt[n], 1.f) : 0.f;
        *(f32x4*)(lds + NLDS_H + swz(e, 2 * c, 256)) = s0;
        *(f32x4*)(lds + NLDS_H + swz(e, 2 * c + 1, 256)) = s1;
        f32x4 v0 = s0 * rc, v1 = s1 * rc;
        *(u32x4*)(lds + NLDS_X + swz(e, 8 + c, 256)) = pack8(v0, v1);
    }
    __syncthreads();
    // phase 0c: column sums of raw segment sums -> acc_e
    if (t < 64) {
        float s = 0.f;
        for (int row = 0; row < 64; ++row)
            s += *(const float*)(lds + NLDS_H + swz(row, t >> 2, 256) + (t & 3) * 4);
        atomicAdd(acc_e + t, s);
    }
    __syncthreads();

    // layer0 (K=128, N=128): Xn -> H
    {
        short8 B[2][4];
#pragma unroll
        for (int n = 0; n < 2; ++n) {
            int col = w * 32 + n * 16 + l15;
#pragma unroll
            for (int ks = 0; ks < 4; ++ks)
                B[n][ks] = *(const short8*)(W0T + col * 128 + ks * 32 + l4 * 8);
        }
        float bb0 = c0n[w * 32 + l15], bb1 = c0n[w * 32 + 16 + l15];
#pragma unroll
        for (int m = 0; m < 4; ++m) {
            f32x4 a0 = {0.f, 0.f, 0.f, 0.f}, a1 = {0.f, 0.f, 0.f, 0.f};
#pragma unroll
            for (int ks = 0; ks < 4; ++ks) {
                short8 a = *(const short8*)(lds + NLDS_X + swz(m * 16 + l15, ks * 4 + l4, 256));
                a0 = mfma16(a, B[0][ks], a0);
                a1 = mfma16(a, B[1][ks], a1);
            }
#pragma unroll
            for (int r = 0; r < 4; ++r) {
                int row = m * 16 + l4 * 4 + r;
                int c0 = w * 32 + l15, c1 = c0 + 16;
                *(unsigned short*)(lds + NLDS_H + swz(row, c0 >> 3, 256) + (c0 & 7) * 2) = f2bf(sp(a0[r] + bb0));
                *(unsigned short*)(lds + NLDS_H + swz(row, c1 >> 3, 256) + (c1 & 7) * 2) = f2bf(sp(a1[r] + bb1));
            }
        }
    }
    __syncthreads();

    // layer1 (K=128, N=128): H -> H1 (Xn region)
    {
        short8 B[2][4];
#pragma unroll
        for (int n = 0; n < 2; ++n) {
            int col = w * 32 + n * 16 + l15;
#pragma unroll
            for (int ks = 0; ks < 4; ++ks)
                B[n][ks] = *(const short8*)(W1T + col * 128 + ks * 32 + l4 * 8);
        }
        float bb0 = b1[w * 32 + l15], bb1 = b1[w * 32 + 16 + l15];
#pragma unroll
        for (int m = 0; m < 4; ++m) {
            f32x4 a0 = {0.f, 0.f, 0.f, 0.f}, a1 = {0.f, 0.f, 0.f, 0.f};
#pragma unroll
            for (int ks = 0; ks < 4; ++ks) {
                short8 a = *(const short8*)(lds + NLDS_H + swz(m * 16 + l15, ks * 4 + l4, 256));
                a0 = mfma16(a, B[0][ks], a0);
                a1 = mfma16(a, B[1][ks], a1);
            }
#pragma unroll
            for (int r = 0; r < 4; ++r) {
                int row = m * 16 + l4 * 4 + r;
                int c0 = w * 32 + l15, c1 = c0 + 16;
                *(unsigned short*)(lds + NLDS_X + swz(row, c0 >> 3, 256) + (c0 & 7) * 2) = f2bf(sp(a0[r] + bb0));
                *(unsigned short*)(lds + NLDS_X + swz(row, c1 >> 3, 256) + (c1 & 7) * 2) = f2bf(sp(a1[r] + bb1));
            }
        }
    }
    __syncthreads();

    // layer2 (K=128, N=64): H1 -> v_new (f32, H region; zero invalid rows)
    {
        const int col = w * 16 + l15;
        short8 B[4];
#pragma unroll
        for (int ks = 0; ks < 4; ++ks)
            B[ks] = *(const short8*)(W2T + col * 128 + ks * 32 + l4 * 8);
        float bb = b2[col];
#pragma unroll
        for (int m = 0; m < 4; ++m) {
            f32x4 acc = {0.f, 0.f, 0.f, 0.f};
#pragma unroll
            for (int ks = 0; ks < 4; ++ks) {
                short8 a = *(const short8*)(lds + NLDS_X + swz(m * 16 + l15, ks * 4 + l4, 256));
                acc = mfma16(a, B[ks], acc);
            }
#pragma unroll
            for (int r = 0; r < 4; ++r) {
                int row = m * 16 + l4 * 4 + r;
                float val = (n0 + row < N) ? sp(acc[r] + bb) : 0.f;
                *(float*)(lds + NLDS_H + swz(row, col >> 2, 256) + (col & 3) * 4) = val;
            }
        }
    }
    __syncthreads();

    // epilogue: skip add + store; column sums -> acc_v
#pragma unroll
    for (int rr = 0; rr < 4; ++rr) {
        int f = t + 256 * rr;
        int e = f >> 4, c = f & 15;
        int n = n0 + e;
        if (n < N) {
            f32x4 vn = *(const f32x4*)(lds + NLDS_H + swz(e, c, 256));
            f32x4 x = *(const f32x4*)(nf + (size_t)n * 64 + c * 4);
            f32x4 o = vn + x;
            *(f32x4*)(vio + (size_t)n * 64 + c * 4) = o;
        }
    }
    if (t < 64) {
        float s = 0.f;
        for (int row = 0; row < 64; ++row)
            s += *(const float*)(lds + NLDS_H + swz(row, t >> 2, 256) + (t & 3) * 4);
        atomicAdd(acc_v + t, s);
    }
}

// ---------------- attr kernel: single block --------------------------------
__global__ void attr_kernel(
    const float* __restrict__ ga, const float* __restrict__ u,
    const float* __restrict__ acc_e, const float* __restrict__ acc_v,
    const float* __restrict__ W0, const float* __restrict__ b0,
    const float* __restrict__ W1, const float* __restrict__ b1,
    const float* __restrict__ W2, const float* __restrict__ b2,
    float* __restrict__ out_u, float Einv, float Ninv)
{
    __shared__ float ain[192];
    __shared__ float h0[128];
    __shared__ float h1[128];
    const int t = threadIdx.x;
    if (t < 64) {
        ain[t] = u[t];
        ain[64 + t] = acc_e[t] * Einv;
        ain[128 + t] = acc_v[t] * Ninv;
    }
    __syncthreads();
    if (t < 128) {
        float a = b0[t];
        for (int k = 0; k < 192; ++k) a += ain[k] * W0[k * 128 + t];
        h0[t] = sp(a);
    }
    __syncthreads();
    if (t < 128) {
        float a = b1[t];
        for (int k = 0; k < 128; ++k) a += h0[k] * W1[k * 128 + t];
        h1[t] = sp(a);
    }
    __syncthreads();
    if (t < 64) {
        float a = b2[t];
        for (int k = 0; k < 128; ++k) a += h1[k] * W2[k * 64 + t];
        out_u[t] = sp(a) + ga[t];
    }
}

// ---------------------------------------------------------------------------
extern "C" void kernel_launch(void* const* d_in, const int* in_sizes, int n_in,
                              void* d_out, int out_size, void* d_ws, size_t ws_size,
                              hipStream_t stream)
{
    const float* edge_feat = (const float*)d_in[0];
    const float* node_feat = (const float*)d_in[1];
    const float* graph_attr = (const float*)d_in[2];
    const int*   src = (const int*)d_in[3];
    const int*   dst = (const int*)d_in[4];
    const float* pre_edge_w = (const float*)d_in[5];
    const float* pre_edge_b = (const float*)d_in[6];
    const float* pre_node_w = (const float*)d_in[7];
    const float* pre_node_b = (const float*)d_in[8];
    const float* pre_attr_w = (const float*)d_in[9];
    const float* pre_attr_b = (const float*)d_in[10];
    const float* edge_w0 = (const float*)d_in[11];
    const float* edge_b0 = (const float*)d_in[12];
    const float* edge_w1 = (const float*)d_in[13];
    const float* edge_b1 = (const float*)d_in[14];
    const float* edge_w2 = (const float*)d_in[15];
    const float* edge_b2 = (const float*)d_in[16];
    const float* node_w0 = (const float*)d_in[17];
    const float* node_b0 = (const float*)d_in[18];
    const float* node_w1 = (const float*)d_in[19];
    const float* node_b1 = (const float*)d_in[20];
    const float* node_w2 = (const float*)d_in[21];
    const float* node_b2 = (const float*)d_in[22];
    const float* attr_w0 = (const float*)d_in[23];
    const float* attr_b0 = (const float*)d_in[24];
    const float* attr_w1 = (const float*)d_in[25];
    const float* attr_b1 = (const float*)d_in[26];
    const float* attr_w2 = (const float*)d_in[27];
    const float* attr_b2 = (const float*)d_in[28];

    const int E = in_sizes[0] / 64;
    const int N = in_sizes[1] / 64;

    // workspace layout
    unsigned short* vb = (unsigned short*)d_ws;          // N*64 bf16
    int*   cnt = (int*)(vb + (size_t)N * 64);            // N
    float* u   = (float*)(cnt + N);                      // 64
    float* c0e = u + 64;                                 // 128
    float* c0n = c0e + 128;                              // 128
    float* acc_e = c0n + 128;                            // 64
    float* acc_v = acc_e + 64;                           // 64
    unsigned short* wT = (unsigned short*)(acc_v + 64);  // 94208 bf16
    unsigned short* WpeT = wT;
    unsigned short* We0T = wT + 4096;
    unsigned short* We1T = wT + 28672;
    unsigned short* We2T = wT + 45056;
    unsigned short* Wn0T = wT + 53248;
    unsigned short* Wn1T = wT + 69632;
    unsigned short* Wn2T = wT + 86016;

    float* e_out = (float*)d_out;                 // E*64
    float* sumE  = e_out + (size_t)E * 64;        // N*64: segment sums, then v_out
    float* u_out = sumE + (size_t)N * 64;         // 64

    hipMemsetAsync(cnt, 0, sizeof(int) * (size_t)N + sizeof(float) * 448, stream);
    hipMemsetAsync(sumE, 0, sizeof(float) * (size_t)N * 64, stream);

    wprep<<<368, 256, 0, stream>>>(pre_edge_w, edge_w0, edge_w1, edge_w2,
                                   node_w0, node_w1, node_w2, wT);
    pre_node_kernel<<<(N + 31) / 32, 256, 0, stream>>>(node_feat, pre_node_w, pre_node_b, vb, N);
    pre_attr_kernel<<<1, 128, 0, stream>>>(graph_attr, pre_attr_w, pre_attr_b,
                                           edge_w0, edge_b0, node_w0, node_b0,
                                           u, c0e, c0n);
    cnt_kernel<<<(E + 255) / 256, 256, 0, stream>>>(dst, cnt, E);
    edge_kernel<<<E / 64, 256, 0, stream>>>(
        edge_feat, vb, src, dst,
        WpeT, pre_edge_b, We0T, c0e, We1T, edge_b1, We2T, edge_b2,
        e_out, sumE);
    node_kernel<<<(N + 63) / 64, 256, 0, stream>>>(
        node_feat, vb, cnt, Wn0T, c0n, Wn1T, node_b1, Wn2T, node_b2,
        sumE, acc_e, acc_v, N);
    attr_kernel<<<1, 128, 0, stream>>>(
        graph_attr, u, acc_e, acc_v,
        attr_w0, attr_b0, attr_w1, attr_b1, attr_w2, attr_b2,
        u_out, 1.f / (float)E, 1.f / (float)N);
}

// Round 3
// 878.521 us; speedup vs baseline: 4.1912x; 1.2997x over previous
//
#include <hip/hip_runtime.h>
#include <cstddef>

// ---------------------------------------------------------------------------
// MegNet block, round 2: swapped-operand bf16 MFMA (packed stores) + cheap
// softplus. E=800000, N=100000, D=64, H=128.
// ---------------------------------------------------------------------------

typedef __attribute__((ext_vector_type(8))) short short8;   // 8 bf16 (4 VGPRs)
typedef __attribute__((ext_vector_type(4))) float f32x4;
typedef __attribute__((ext_vector_type(4))) unsigned int u32x4;
typedef __attribute__((ext_vector_type(2))) unsigned int u32x2;

__device__ __forceinline__ float sp(float x) {
    // softplus via hw exp/log: max(x,0) + log(1 + exp(-|x|))
    return fmaxf(x, 0.f) + __logf(1.f + __expf(-fabsf(x)));
}
__device__ __forceinline__ unsigned short f2bf(float x) {
    unsigned int u = __float_as_uint(x);
    u += 0x7fff + ((u >> 16) & 1);          // RNE
    return (unsigned short)(u >> 16);
}
__device__ __forceinline__ unsigned int cvtpk(float lo, float hi) {
    unsigned int r;
    asm("v_cvt_pk_bf16_f32 %0, %1, %2" : "=v"(r) : "v"(lo), "v"(hi));
    return r;
}
__device__ __forceinline__ u32x4 pack8(f32x4 a, f32x4 b) {
    u32x4 r;
    r.x = cvtpk(a[0], a[1]); r.y = cvtpk(a[2], a[3]);
    r.z = cvtpk(b[0], b[1]); r.w = cvtpk(b[2], b[3]);
    return r;
}
// 16B-chunk XOR swizzle: byte offset for (row, chunk) in a tile of row stride S
__device__ __forceinline__ int swz(int row, int chunk, int stride) {
    return row * stride + 128 * (chunk >> 3) + 16 * ((chunk & 7) ^ (row & 7));
}
__device__ __forceinline__ f32x4 mfma16(short8 a, short8 b, f32x4 c) {
    return __builtin_amdgcn_mfma_f32_16x16x32_bf16(a, b, c, 0, 0, 0);
}

// ---------------- weight transpose+bf16 prep -------------------------------
// out layout (bf16, [N][K] row-major each):
//   WpeT @0 (64x64), We0T @4096 (128x192), We1T @28672 (128x128),
//   We2T @45056 (64x128), Wn0T @53248 (128x128), Wn1T @69632 (128x128),
//   Wn2T @86016 (64x128), WpnT @94208 (64x64); total 98304
__global__ __launch_bounds__(256) void wprep(
    const float* __restrict__ Wpe, const float* __restrict__ We0,
    const float* __restrict__ We1, const float* __restrict__ We2,
    const float* __restrict__ Wn0, const float* __restrict__ Wn1,
    const float* __restrict__ Wn2, const float* __restrict__ Wpn,
    unsigned short* __restrict__ out)
{
    int idx = blockIdx.x * 256 + threadIdx.x;
    const float* src; int K, N, base;
    if      (idx < 4096)  { src = Wpe; K = 64;  N = 64;  base = 0; }
    else if (idx < 28672) { src = We0; K = 192; N = 128; base = 4096; }
    else if (idx < 45056) { src = We1; K = 128; N = 128; base = 28672; }
    else if (idx < 53248) { src = We2; K = 128; N = 64;  base = 45056; }
    else if (idx < 69632) { src = Wn0; K = 128; N = 128; base = 53248; }
    else if (idx < 86016) { src = Wn1; K = 128; N = 128; base = 69632; }
    else if (idx < 94208) { src = Wn2; K = 128; N = 64;  base = 86016; }
    else if (idx < 98304) { src = Wpn; K = 64;  N = 64;  base = 94208; }
    else return;
    int r = idx - base, n = r / K, k = r % K;
    out[idx] = f2bf(src[(size_t)k * N + n]);
}

// ---------------- pre-dense node MLP (MFMA) -> bf16 v ----------------------
// LDS: X [64][64] bf16 s128 @0 (8192) | O [64][64] bf16 s128 @8192 (8192)
__global__ __launch_bounds__(256) void pre_node_kernel(
    const float* __restrict__ nf, const unsigned short* __restrict__ WpnT,
    const float* __restrict__ b, unsigned short* __restrict__ vb, int N)
{
    __shared__ __align__(16) char lds[16384];
    const int t = threadIdx.x, w = t >> 6, l = t & 63;
    const int l15 = l & 15, l4 = l >> 4;
    const int n0 = blockIdx.x * 64;

#pragma unroll
    for (int rr = 0; rr < 2; ++rr) {
        int f = t + 256 * rr;
        int e = f >> 3, c = f & 7;
        int n = n0 + e; if (n >= N) n = N - 1;
        const float* p = nf + (size_t)n * 64 + c * 8;
        f32x4 x0 = *(const f32x4*)p, x1 = *(const f32x4*)(p + 4);
        *(u32x4*)(lds + swz(e, c, 128)) = pack8(x0, x1);
    }
    __syncthreads();
    {
        const int nr = w * 16;
        short8 A0 = *(const short8*)(WpnT + (nr + l15) * 64 + l4 * 8);
        short8 A1 = *(const short8*)(WpnT + (nr + l15) * 64 + 32 + l4 * 8);
        f32x4 bb = *(const f32x4*)(b + nr + l4 * 4);
        const int ochunk = (nr >> 3) + (l4 >> 1), obyte = (l4 & 1) * 8;
#pragma unroll
        for (int tt = 0; tt < 4; ++tt) {
            short8 b0 = *(const short8*)(lds + swz(tt * 16 + l15, l4, 128));
            short8 b1 = *(const short8*)(lds + swz(tt * 16 + l15, 4 + l4, 128));
            f32x4 acc = {0.f, 0.f, 0.f, 0.f};
            acc = mfma16(A0, b0, acc);
            acc = mfma16(A1, b1, acc);
            u32x2 p;
            p.x = cvtpk(sp(acc[0] + bb[0]), sp(acc[1] + bb[1]));
            p.y = cvtpk(sp(acc[2] + bb[2]), sp(acc[3] + bb[3]));
            *(u32x2*)(lds + 8192 + swz(tt * 16 + l15, ochunk, 128) + obyte) = p;
        }
    }
    __syncthreads();
#pragma unroll
    for (int rr = 0; rr < 2; ++rr) {
        int f = t + 256 * rr;
        int e = f >> 3, c = f & 7;
        int n = n0 + e;
        if (n < N) {
            u32x4 d = *(const u32x4*)(lds + 8192 + swz(e, c, 128));
            *(u32x4*)(vb + (size_t)n * 64 + c * 8) = d;
        }
    }
}

// -------- pre-dense attr + fold u into edge/node layer-0 biases ------------
__global__ void pre_attr_kernel(
    const float* __restrict__ ga, const float* __restrict__ Wpa, const float* __restrict__ bpa,
    const float* __restrict__ eW0, const float* __restrict__ eb0,
    const float* __restrict__ nW0, const float* __restrict__ nb0,
    float* __restrict__ u, float* __restrict__ c0e, float* __restrict__ c0n)
{
    __shared__ float us[64];
    const int t = threadIdx.x;
    if (t < 64) {
        float acc = bpa[t];
        for (int k = 0; k < 64; ++k) acc += ga[k] * Wpa[k * 64 + t];
        float uu = sp(acc);
        us[t] = uu;
        u[t] = uu;
    }
    __syncthreads();
    if (t < 128) {
        float acc = eb0[t];
        for (int k = 0; k < 64; ++k) acc += us[k] * eW0[(192 + k) * 128 + t];
        c0e[t] = acc;
        float accn = nb0[t];
        for (int k = 0; k < 64; ++k) accn += us[k] * nW0[(128 + k) * 128 + t];
        c0n[t] = accn;
    }
}

// ---------------- incoming-edge counts per node ----------------------------
__global__ __launch_bounds__(256) void cnt_kernel(
    const int* __restrict__ dst, int* __restrict__ cnt, int E)
{
    int i = blockIdx.x * 256 + threadIdx.x;
    if (i < E) atomicAdd(&cnt[dst[i]], 1);
}

// ---------------- edge kernel: 64 edges / block, 4 waves, MFMA -------------
// LDS: X [64][192] bf16 s384 @0 (24576) | EF [64][64] bf16 s128 @24576 (8192)
//      H0 [64][128] bf16 s256 @32768 (16384)  -> total 49152
// H1 reuses X region (s256); e_new f32 [64][64] s256 reuses H0 region.
#define ELDS_X  0
#define ELDS_EF 24576
#define ELDS_H  32768

__global__ __launch_bounds__(256, 3) void edge_kernel(
    const float* __restrict__ ef, const unsigned short* __restrict__ vb,
    const int* __restrict__ src, const int* __restrict__ dst,
    const unsigned short* __restrict__ WpeT, const float* __restrict__ bpe,
    const unsigned short* __restrict__ W0T, const float* __restrict__ c0e,
    const unsigned short* __restrict__ W1T, const float* __restrict__ b1,
    const unsigned short* __restrict__ W2T, const float* __restrict__ b2,
    float* __restrict__ e_out, float* __restrict__ sumE)
{
    __shared__ __align__(16) char lds[49152];
    const int t = threadIdx.x;
    const int w = t >> 6, l = t & 63;
    const int l15 = l & 15, l4 = l >> 4;
    const int e0 = blockIdx.x * 64;

    // phase 0a: edge features fp32 -> bf16 LDS
#pragma unroll
    for (int rr = 0; rr < 2; ++rr) {
        int f = t + 256 * rr;
        int e = f >> 3, c = f & 7;
        const float* p = ef + (size_t)(e0 + e) * 64 + c * 8;
        f32x4 x0 = *(const f32x4*)p, x1 = *(const f32x4*)(p + 4);
        *(u32x4*)(lds + ELDS_EF + swz(e, c, 128)) = pack8(x0, x1);
    }
    // phase 0b: gather v[src], v[dst] (bf16)
#pragma unroll
    for (int rr = 0; rr < 4; ++rr) {
        int f = t + 256 * rr;
        int e = f >> 4, c = f & 15;
        int node = (c < 8) ? src[e0 + e] : dst[e0 + e];
        u32x4 d = *(const u32x4*)(vb + (size_t)node * 64 + (c & 7) * 8);
        *(u32x4*)(lds + ELDS_X + swz(e, c, 384)) = d;
    }
    __syncthreads();

    // phase 1: pre-dense edge MLP (K=64, N=64) -> X cols 128..191
    {
        const int nr = w * 16;
        short8 A0 = *(const short8*)(WpeT + (nr + l15) * 64 + l4 * 8);
        short8 A1 = *(const short8*)(WpeT + (nr + l15) * 64 + 32 + l4 * 8);
        f32x4 bb = *(const f32x4*)(bpe + nr + l4 * 4);
        const int ochunk = ((128 + nr) >> 3) + (l4 >> 1), obyte = (l4 & 1) * 8;
#pragma unroll
        for (int tt = 0; tt < 4; ++tt) {
            short8 b0 = *(const short8*)(lds + ELDS_EF + swz(tt * 16 + l15, l4, 128));
            short8 b1 = *(const short8*)(lds + ELDS_EF + swz(tt * 16 + l15, 4 + l4, 128));
            f32x4 acc = {0.f, 0.f, 0.f, 0.f};
            acc = mfma16(A0, b0, acc);
            acc = mfma16(A1, b1, acc);
            u32x2 p;
            p.x = cvtpk(sp(acc[0] + bb[0]), sp(acc[1] + bb[1]));
            p.y = cvtpk(sp(acc[2] + bb[2]), sp(acc[3] + bb[3]));
            *(u32x2*)(lds + ELDS_X + swz(tt * 16 + l15, ochunk, 384) + obyte) = p;
        }
    }
    __syncthreads();

    // phase 2: layer0 (K=192, N=128) -> H0
    {
        const int nr0 = w * 32, nr1 = nr0 + 16;
        short8 A[2][6];
#pragma unroll
        for (int a = 0; a < 2; ++a)
#pragma unroll
            for (int ks = 0; ks < 6; ++ks)
                A[a][ks] = *(const short8*)(W0T + (nr0 + a * 16 + l15) * 192 + ks * 32 + l4 * 8);
        f32x4 bb0 = *(const f32x4*)(c0e + nr0 + l4 * 4);
        f32x4 bb1 = *(const f32x4*)(c0e + nr1 + l4 * 4);
        const int oc0 = (nr0 >> 3) + (l4 >> 1), oc1 = (nr1 >> 3) + (l4 >> 1);
        const int obyte = (l4 & 1) * 8;
#pragma unroll
        for (int tt = 0; tt < 4; ++tt) {
            f32x4 a0 = {0.f, 0.f, 0.f, 0.f}, a1 = {0.f, 0.f, 0.f, 0.f};
#pragma unroll
            for (int ks = 0; ks < 6; ++ks) {
                short8 b = *(const short8*)(lds + ELDS_X + swz(tt * 16 + l15, ks * 4 + l4, 384));
                a0 = mfma16(A[0][ks], b, a0);
                a1 = mfma16(A[1][ks], b, a1);
            }
            u32x2 p0, p1;
            p0.x = cvtpk(sp(a0[0] + bb0[0]), sp(a0[1] + bb0[1]));
            p0.y = cvtpk(sp(a0[2] + bb0[2]), sp(a0[3] + bb0[3]));
            p1.x = cvtpk(sp(a1[0] + bb1[0]), sp(a1[1] + bb1[1]));
            p1.y = cvtpk(sp(a1[2] + bb1[2]), sp(a1[3] + bb1[3]));
            *(u32x2*)(lds + ELDS_H + swz(tt * 16 + l15, oc0, 256) + obyte) = p0;
            *(u32x2*)(lds + ELDS_H + swz(tt * 16 + l15, oc1, 256) + obyte) = p1;
        }
    }
    __syncthreads();

    // phase 3: layer1 (K=128, N=128): H0 -> H1 (X region, s256)
    {
        const int nr0 = w * 32, nr1 = nr0 + 16;
        short8 A[2][4];
#pragma unroll
        for (int a = 0; a < 2; ++a)
#pragma unroll
            for (int ks = 0; ks < 4; ++ks)
                A[a][ks] = *(const short8*)(W1T + (nr0 + a * 16 + l15) * 128 + ks * 32 + l4 * 8);
        f32x4 bb0 = *(const f32x4*)(b1 + nr0 + l4 * 4);
        f32x4 bb1 = *(const f32x4*)(b1 + nr1 + l4 * 4);
        const int oc0 = (nr0 >> 3) + (l4 >> 1), oc1 = (nr1 >> 3) + (l4 >> 1);
        const int obyte = (l4 & 1) * 8;
#pragma unroll
        for (int tt = 0; tt < 4; ++tt) {
            f32x4 a0 = {0.f, 0.f, 0.f, 0.f}, a1 = {0.f, 0.f, 0.f, 0.f};
#pragma unroll
            for (int ks = 0; ks < 4; ++ks) {
                short8 b = *(const short8*)(lds + ELDS_H + swz(tt * 16 + l15, ks * 4 + l4, 256));
                a0 = mfma16(A[0][ks], b, a0);
                a1 = mfma16(A[1][ks], b, a1);
            }
            u32x2 p0, p1;
            p0.x = cvtpk(sp(a0[0] + bb0[0]), sp(a0[1] + bb0[1]));
            p0.y = cvtpk(sp(a0[2] + bb0[2]), sp(a0[3] + bb0[3]));
            p1.x = cvtpk(sp(a1[0] + bb1[0]), sp(a1[1] + bb1[1]));
            p1.y = cvtpk(sp(a1[2] + bb1[2]), sp(a1[3] + bb1[3]));
            *(u32x2*)(lds + ELDS_X + swz(tt * 16 + l15, oc0, 256) + obyte) = p0;
            *(u32x2*)(lds + ELDS_X + swz(tt * 16 + l15, oc1, 256) + obyte) = p1;
        }
    }
    __syncthreads();

    // phase 4: layer2 (K=128, N=64): H1 -> e_new (f32, H0 region)
    {
        const int nr = w * 16;
        short8 A[4];
#pragma unroll
        for (int ks = 0; ks < 4; ++ks)
            A[ks] = *(const short8*)(W2T + (nr + l15) * 128 + ks * 32 + l4 * 8);
        f32x4 bb = *(const f32x4*)(b2 + nr + l4 * 4);
        const int ochunk = (nr >> 2) + l4;
#pragma unroll
        for (int tt = 0; tt < 4; ++tt) {
            f32x4 acc = {0.f, 0.f, 0.f, 0.f};
#pragma unroll
            for (int ks = 0; ks < 4; ++ks) {
                short8 b = *(const short8*)(lds + ELDS_X + swz(tt * 16 + l15, ks * 4 + l4, 256));
                acc = mfma16(A[ks], b, acc);
            }
            f32x4 y = {sp(acc[0] + bb[0]), sp(acc[1] + bb[1]),
                       sp(acc[2] + bb[2]), sp(acc[3] + bb[3])};
            *(f32x4*)(lds + ELDS_H + swz(tt * 16 + l15, ochunk, 256)) = y;
        }
    }
    __syncthreads();

    // phase 5: epilogue — skip add, store, segment-sum atomics
#pragma unroll
    for (int rr = 0; rr < 4; ++rr) {
        int f = t + 256 * rr;
        int e = f >> 4, c = f & 15;
        f32x4 en = *(const f32x4*)(lds + ELDS_H + swz(e, c, 256));
        f32x4 ei = *(const f32x4*)(ef + (size_t)(e0 + e) * 64 + c * 4);
        f32x4 o = en + ei;
        *(f32x4*)(e_out + (size_t)(e0 + e) * 64 + c * 4) = o;
        int d = dst[e0 + e];
        float* sb = sumE + (size_t)d * 64 + c * 4;
        atomicAdd(sb + 0, en[0]); atomicAdd(sb + 1, en[1]);
        atomicAdd(sb + 2, en[2]); atomicAdd(sb + 3, en[3]);
    }
}

// ---------------- node kernel: 64 nodes / block, MFMA ----------------------
// LDS: Xn [64][128] bf16 s256 @0 (16384) | H [64][128] bf16 s256 @16384 (16384)
#define NLDS_X 0
#define NLDS_H 16384

__global__ __launch_bounds__(256, 3) void node_kernel(
    const float* __restrict__ nf, const unsigned short* __restrict__ vb,
    const int* __restrict__ cnt,
    const unsigned short* __restrict__ W0T, const float* __restrict__ c0n,
    const unsigned short* __restrict__ W1T, const float* __restrict__ b1,
    const unsigned short* __restrict__ W2T, const float* __restrict__ b2,
    float* vio, float* __restrict__ acc_e, float* __restrict__ acc_v, int N)
{
    __shared__ __align__(16) char lds[32768];
    const int t = threadIdx.x;
    const int w = t >> 6, l = t & 63;
    const int l15 = l & 15, l4 = l >> 4;
    const int n0 = blockIdx.x * 64;

    // phase 0a: v (bf16) rows -> Xn cols 0..63
#pragma unroll
    for (int rr = 0; rr < 2; ++rr) {
        int f = t + 256 * rr;
        int e = f >> 3, c = f & 7;
        int n = n0 + e; if (n >= N) n = N - 1;
        u32x4 d = *(const u32x4*)(vb + (size_t)n * 64 + c * 8);
        *(u32x4*)(lds + NLDS_X + swz(e, c, 256)) = d;
    }
    // phase 0b: segment sums -> raw f32 (H region) + ve bf16 (Xn cols 64..127)
#pragma unroll
    for (int rr = 0; rr < 2; ++rr) {
        int f = t + 256 * rr;
        int e = f >> 3, c = f & 7;
        int n = n0 + e;
        bool valid = n < N;
        int ns = valid ? n : N - 1;
        const float* p = vio + (size_t)ns * 64 + c * 8;
        f32x4 s0 = *(const f32x4*)p, s1 = *(const f32x4*)(p + 4);
        f32x4 z = {0.f, 0.f, 0.f, 0.f};
        if (!valid) { s0 = z; s1 = z; }
        float rc = valid ? 1.f / fmaxf((float)cnt[n], 1.f) : 0.f;
        *(f32x4*)(lds + NLDS_H + swz(e, 2 * c, 256)) = s0;
        *(f32x4*)(lds + NLDS_H + swz(e, 2 * c + 1, 256)) = s1;
        f32x4 v0 = s0 * rc, v1 = s1 * rc;
        *(u32x4*)(lds + NLDS_X + swz(e, 8 + c, 256)) = pack8(v0, v1);
    }
    __syncthreads();
    // phase 0c: column sums of raw segment sums -> acc_e
    if (t < 64) {
        float s = 0.f;
        for (int row = 0; row < 64; ++row)
            s += *(const float*)(lds + NLDS_H + swz(row, t >> 2, 256) + (t & 3) * 4);
        atomicAdd(acc_e + t, s);
    }
    __syncthreads();

    // layer0 (K=128, N=128): Xn -> H
    {
        const int nr0 = w * 32, nr1 = nr0 + 16;
        short8 A[2][4];
#pragma unroll
        for (int a = 0; a < 2; ++a)
#pragma unroll
            for (int ks = 0; ks < 4; ++ks)
                A[a][ks] = *(const short8*)(W0T + (nr0 + a * 16 + l15) * 128 + ks * 32 + l4 * 8);
        f32x4 bb0 = *(const f32x4*)(c0n + nr0 + l4 * 4);
        f32x4 bb1 = *(const f32x4*)(c0n + nr1 + l4 * 4);
        const int oc0 = (nr0 >> 3) + (l4 >> 1), oc1 = (nr1 >> 3) + (l4 >> 1);
        const int obyte = (l4 & 1) * 8;
#pragma unroll
        for (int tt = 0; tt < 4; ++tt) {
            f32x4 a0 = {0.f, 0.f, 0.f, 0.f}, a1 = {0.f, 0.f, 0.f, 0.f};
#pragma unroll
            for (int ks = 0; ks < 4; ++ks) {
                short8 b = *(const short8*)(lds + NLDS_X + swz(tt * 16 + l15, ks * 4 + l4, 256));
                a0 = mfma16(A[0][ks], b, a0);
                a1 = mfma16(A[1][ks], b, a1);
            }
            u32x2 p0, p1;
            p0.x = cvtpk(sp(a0[0] + bb0[0]), sp(a0[1] + bb0[1]));
            p0.y = cvtpk(sp(a0[2] + bb0[2]), sp(a0[3] + bb0[3]));
            p1.x = cvtpk(sp(a1[0] + bb1[0]), sp(a1[1] + bb1[1]));
            p1.y = cvtpk(sp(a1[2] + bb1[2]), sp(a1[3] + bb1[3]));
            *(u32x2*)(lds + NLDS_H + swz(tt * 16 + l15, oc0, 256) + obyte) = p0;
            *(u32x2*)(lds + NLDS_H + swz(tt * 16 + l15, oc1, 256) + obyte) = p1;
        }
    }
    __syncthreads();

    // layer1 (K=128, N=128): H -> H1 (Xn region)
    {
        const int nr0 = w * 32, nr1 = nr0 + 16;
        short8 A[2][4];
#pragma unroll
        for (int a = 0; a < 2; ++a)
#pragma unroll
            for (int ks = 0; ks < 4; ++ks)
                A[a][ks] = *(const short8*)(W1T + (nr0 + a * 16 + l15) * 128 + ks * 32 + l4 * 8);
        f32x4 bb0 = *(const f32x4*)(b1 + nr0 + l4 * 4);
        f32x4 bb1 = *(const f32x4*)(b1 + nr1 + l4 * 4);
        const int oc0 = (nr0 >> 3) + (l4 >> 1), oc1 = (nr1 >> 3) + (l4 >> 1);
        const int obyte = (l4 & 1) * 8;
#pragma unroll
        for (int tt = 0; tt < 4; ++tt) {
            f32x4 a0 = {0.f, 0.f, 0.f, 0.f}, a1 = {0.f, 0.f, 0.f, 0.f};
#pragma unroll
            for (int ks = 0; ks < 4; ++ks) {
                short8 b = *(const short8*)(lds + NLDS_H + swz(tt * 16 + l15, ks * 4 + l4, 256));
                a0 = mfma16(A[0][ks], b, a0);
                a1 = mfma16(A[1][ks], b, a1);
            }
            u32x2 p0, p1;
            p0.x = cvtpk(sp(a0[0] + bb0[0]), sp(a0[1] + bb0[1]));
            p0.y = cvtpk(sp(a0[2] + bb0[2]), sp(a0[3] + bb0[3]));
            p1.x = cvtpk(sp(a1[0] + bb1[0]), sp(a1[1] + bb1[1]));
            p1.y = cvtpk(sp(a1[2] + bb1[2]), sp(a1[3] + bb1[3]));
            *(u32x2*)(lds + NLDS_X + swz(tt * 16 + l15, oc0, 256) + obyte) = p0;
            *(u32x2*)(lds + NLDS_X + swz(tt * 16 + l15, oc1, 256) + obyte) = p1;
        }
    }
    __syncthreads();

    // layer2 (K=128, N=64): H1 -> v_new (f32, H region; zero invalid cols)
    {
        const int nr = w * 16;
        short8 A[4];
#pragma unroll
        for (int ks = 0; ks < 4; ++ks)
            A[ks] = *(const short8*)(W2T + (nr + l15) * 128 + ks * 32 + l4 * 8);
        f32x4 bb = *(const f32x4*)(b2 + nr + l4 * 4);
        const int ochunk = (nr >> 2) + l4;
#pragma unroll
        for (int tt = 0; tt < 4; ++tt) {
            f32x4 acc = {0.f, 0.f, 0.f, 0.f};
#pragma unroll
            for (int ks = 0; ks < 4; ++ks) {
                short8 b = *(const short8*)(lds + NLDS_X + swz(tt * 16 + l15, ks * 4 + l4, 256));
                acc = mfma16(A[ks], b, acc);
            }
            bool valid = (n0 + tt * 16 + l15) < N;
            f32x4 y;
            y[0] = valid ? sp(acc[0] + bb[0]) : 0.f;
            y[1] = valid ? sp(acc[1] + bb[1]) : 0.f;
            y[2] = valid ? sp(acc[2] + bb[2]) : 0.f;
            y[3] = valid ? sp(acc[3] + bb[3]) : 0.f;
            *(f32x4*)(lds + NLDS_H + swz(tt * 16 + l15, ochunk, 256)) = y;
        }
    }
    __syncthreads();

    // epilogue: skip add + store; column sums -> acc_v
#pragma unroll
    for (int rr = 0; rr < 4; ++rr) {
        int f = t + 256 * rr;
        int e = f >> 4, c = f & 15;
        int n = n0 + e;
        if (n < N) {
            f32x4 vn = *(const f32x4*)(lds + NLDS_H + swz(e, c, 256));
            f32x4 x = *(const f32x4*)(nf + (size_t)n * 64 + c * 4);
            f32x4 o = vn + x;
            *(f32x4*)(vio + (size_t)n * 64 + c * 4) = o;
        }
    }
    if (t < 64) {
        float s = 0.f;
        for (int row = 0; row < 64; ++row)
            s += *(const float*)(lds + NLDS_H + swz(row, t >> 2, 256) + (t & 3) * 4);
        atomicAdd(acc_v + t, s);
    }
}

// ---------------- attr kernel: single block --------------------------------
__global__ void attr_kernel(
    const float* __restrict__ ga, const float* __restrict__ u,
    const float* __restrict__ acc_e, const float* __restrict__ acc_v,
    const float* __restrict__ W0, const float* __restrict__ b0,
    const float* __restrict__ W1, const float* __restrict__ b1,
    const float* __restrict__ W2, const float* __restrict__ b2,
    float* __restrict__ out_u, float Einv, float Ninv)
{
    __shared__ float ain[192];
    __shared__ float h0[128];
    __shared__ float h1[128];
    const int t = threadIdx.x;
    if (t < 64) {
        ain[t] = u[t];
        ain[64 + t] = acc_e[t] * Einv;
        ain[128 + t] = acc_v[t] * Ninv;
    }
    __syncthreads();
    if (t < 128) {
        float a = b0[t];
        for (int k = 0; k < 192; ++k) a += ain[k] * W0[k * 128 + t];
        h0[t] = sp(a);
    }
    __syncthreads();
    if (t < 128) {
        float a = b1[t];
        for (int k = 0; k < 128; ++k) a += h0[k] * W1[k * 128 + t];
        h1[t] = sp(a);
    }
    __syncthreads();
    if (t < 64) {
        float a = b2[t];
        for (int k = 0; k < 128; ++k) a += h1[k] * W2[k * 64 + t];
        out_u[t] = sp(a) + ga[t];
    }
}

// ---------------------------------------------------------------------------
extern "C" void kernel_launch(void* const* d_in, const int* in_sizes, int n_in,
                              void* d_out, int out_size, void* d_ws, size_t ws_size,
                              hipStream_t stream)
{
    const float* edge_feat = (const float*)d_in[0];
    const float* node_feat = (const float*)d_in[1];
    const float* graph_attr = (const float*)d_in[2];
    const int*   src = (const int*)d_in[3];
    const int*   dst = (const int*)d_in[4];
    const float* pre_edge_w = (const float*)d_in[5];
    const float* pre_edge_b = (const float*)d_in[6];
    const float* pre_node_w = (const float*)d_in[7];
    const float* pre_node_b = (const float*)d_in[8];
    const float* pre_attr_w = (const float*)d_in[9];
    const float* pre_attr_b = (const float*)d_in[10];
    const float* edge_w0 = (const float*)d_in[11];
    const float* edge_b0 = (const float*)d_in[12];
    const float* edge_w1 = (const float*)d_in[13];
    const float* edge_b1 = (const float*)d_in[14];
    const float* edge_w2 = (const float*)d_in[15];
    const float* edge_b2 = (const float*)d_in[16];
    const float* node_w0 = (const float*)d_in[17];
    const float* node_b0 = (const float*)d_in[18];
    const float* node_w1 = (const float*)d_in[19];
    const float* node_b1 = (const float*)d_in[20];
    const float* node_w2 = (const float*)d_in[21];
    const float* node_b2 = (const float*)d_in[22];
    const float* attr_w0 = (const float*)d_in[23];
    const float* attr_b0 = (const float*)d_in[24];
    const float* attr_w1 = (const float*)d_in[25];
    const float* attr_b1 = (const float*)d_in[26];
    const float* attr_w2 = (const float*)d_in[27];
    const float* attr_b2 = (const float*)d_in[28];

    const int E = in_sizes[0] / 64;
    const int N = in_sizes[1] / 64;

    // workspace layout
    unsigned short* vb = (unsigned short*)d_ws;          // N*64 bf16
    int*   cnt = (int*)(vb + (size_t)N * 64);            // N
    float* u   = (float*)(cnt + N);                      // 64
    float* c0e = u + 64;                                 // 128
    float* c0n = c0e + 128;                              // 128
    float* acc_e = c0n + 128;                            // 64
    float* acc_v = acc_e + 64;                           // 64
    unsigned short* wT = (unsigned short*)(acc_v + 64);  // 98304 bf16
    unsigned short* WpeT = wT;
    unsigned short* We0T = wT + 4096;
    unsigned short* We1T = wT + 28672;
    unsigned short* We2T = wT + 45056;
    unsigned short* Wn0T = wT + 53248;
    unsigned short* Wn1T = wT + 69632;
    unsigned short* Wn2T = wT + 86016;
    unsigned short* WpnT = wT + 94208;

    float* e_out = (float*)d_out;                 // E*64
    float* sumE  = e_out + (size_t)E * 64;        // N*64: segment sums, then v_out
    float* u_out = sumE + (size_t)N * 64;         // 64

    hipMemsetAsync(cnt, 0, sizeof(int) * (size_t)N + sizeof(float) * 448, stream);
    hipMemsetAsync(sumE, 0, sizeof(float) * (size_t)N * 64, stream);

    wprep<<<384, 256, 0, stream>>>(pre_edge_w, edge_w0, edge_w1, edge_w2,
                                   node_w0, node_w1, node_w2, pre_node_w, wT);
    pre_node_kernel<<<(N + 63) / 64, 256, 0, stream>>>(node_feat, WpnT, pre_node_b, vb, N);
    pre_attr_kernel<<<1, 128, 0, stream>>>(graph_attr, pre_attr_w, pre_attr_b,
                                           edge_w0, edge_b0, node_w0, node_b0,
                                           u, c0e, c0n);
    cnt_kernel<<<(E + 255) / 256, 256, 0, stream>>>(dst, cnt, E);
    edge_kernel<<<E / 64, 256, 0, stream>>>(
        edge_feat, vb, src, dst,
        WpeT, pre_edge_b, We0T, c0e, We1T, edge_b1, We2T, edge_b2,
        e_out, sumE);
    node_kernel<<<(N + 63) / 64, 256, 0, stream>>>(
        node_feat, vb, cnt, Wn0T, c0n, Wn1T, node_b1, Wn2T, node_b2,
        sumE, acc_e, acc_v, N);
    attr_kernel<<<1, 128, 0, stream>>>(
        graph_attr, u, acc_e, acc_v,
        attr_w0, attr_b0, attr_w1, attr_b1, attr_w2, attr_b2,
        u_out, 1.f / (float)E, 1.f / (float)N);
}

// Round 5
// 710.750 us; speedup vs baseline: 5.1805x; 1.2360x over previous
//
#include <hip/hip_runtime.h>
#include <cstddef>

// ---------------------------------------------------------------------------
// MegNet block, round 4: round-3 structure (CSR segment-sum, 32-edge tile)
// with the accumulator-zeroing bug fixed (acc_e/acc_v fully memset each call).
// E=800000, N=100000, D=64, H=128.
// ---------------------------------------------------------------------------

typedef __attribute__((ext_vector_type(8))) short short8;   // 8 bf16
typedef __attribute__((ext_vector_type(4))) float f32x4;
typedef __attribute__((ext_vector_type(4))) unsigned int u32x4;
typedef __attribute__((ext_vector_type(2))) unsigned int u32x2;

__device__ __forceinline__ float sp(float x) {
    return fmaxf(x, 0.f) + __logf(1.f + __expf(-fabsf(x)));
}
__device__ __forceinline__ unsigned short f2bf(float x) {
    unsigned int u = __float_as_uint(x);
    u += 0x7fff + ((u >> 16) & 1);          // RNE
    return (unsigned short)(u >> 16);
}
__device__ __forceinline__ unsigned int cvtpk(float lo, float hi) {
    unsigned int r;
    asm("v_cvt_pk_bf16_f32 %0, %1, %2" : "=v"(r) : "v"(lo), "v"(hi));
    return r;
}
__device__ __forceinline__ u32x4 pack8(f32x4 a, f32x4 b) {
    u32x4 r;
    r.x = cvtpk(a[0], a[1]); r.y = cvtpk(a[2], a[3]);
    r.z = cvtpk(b[0], b[1]); r.w = cvtpk(b[2], b[3]);
    return r;
}
__device__ __forceinline__ float bflo(unsigned int u) { return __uint_as_float(u << 16); }
__device__ __forceinline__ float bfhi(unsigned int u) { return __uint_as_float(u & 0xffff0000u); }
// 16B-chunk XOR swizzle
__device__ __forceinline__ int swz(int row, int chunk, int stride) {
    return row * stride + 128 * (chunk >> 3) + 16 * ((chunk & 7) ^ (row & 7));
}
__device__ __forceinline__ f32x4 mfma16(short8 a, short8 b, f32x4 c) {
    return __builtin_amdgcn_mfma_f32_16x16x32_bf16(a, b, c, 0, 0, 0);
}

// ---------------- weight transpose+bf16 prep -------------------------------
__global__ __launch_bounds__(256) void wprep(
    const float* __restrict__ Wpe, const float* __restrict__ We0,
    const float* __restrict__ We1, const float* __restrict__ We2,
    const float* __restrict__ Wn0, const float* __restrict__ Wn1,
    const float* __restrict__ Wn2, const float* __restrict__ Wpn,
    unsigned short* __restrict__ out)
{
    int idx = blockIdx.x * 256 + threadIdx.x;
    const float* src; int K, N, base;
    if      (idx < 4096)  { src = Wpe; K = 64;  N = 64;  base = 0; }
    else if (idx < 28672) { src = We0; K = 192; N = 128; base = 4096; }
    else if (idx < 45056) { src = We1; K = 128; N = 128; base = 28672; }
    else if (idx < 53248) { src = We2; K = 128; N = 64;  base = 45056; }
    else if (idx < 69632) { src = Wn0; K = 128; N = 128; base = 53248; }
    else if (idx < 86016) { src = Wn1; K = 128; N = 128; base = 69632; }
    else if (idx < 94208) { src = Wn2; K = 128; N = 64;  base = 86016; }
    else if (idx < 98304) { src = Wpn; K = 64;  N = 64;  base = 94208; }
    else return;
    int r = idx - base, n = r / K, k = r % K;
    out[idx] = f2bf(src[(size_t)k * N + n]);
}

// ---------------- pre-dense node MLP (MFMA) -> bf16 v ----------------------
__global__ __launch_bounds__(256) void pre_node_kernel(
    const float* __restrict__ nf, const unsigned short* __restrict__ WpnT,
    const float* __restrict__ b, unsigned short* __restrict__ vb, int N)
{
    __shared__ __align__(16) char lds[16384];
    const int t = threadIdx.x, w = t >> 6, l = t & 63;
    const int l15 = l & 15, l4 = l >> 4;
    const int n0 = blockIdx.x * 64;

#pragma unroll
    for (int rr = 0; rr < 2; ++rr) {
        int f = t + 256 * rr;
        int e = f >> 3, c = f & 7;
        int n = n0 + e; if (n >= N) n = N - 1;
        const float* p = nf + (size_t)n * 64 + c * 8;
        f32x4 x0 = *(const f32x4*)p, x1 = *(const f32x4*)(p + 4);
        *(u32x4*)(lds + swz(e, c, 128)) = pack8(x0, x1);
    }
    __syncthreads();
    {
        const int nr = w * 16;
        short8 A0 = *(const short8*)(WpnT + (nr + l15) * 64 + l4 * 8);
        short8 A1 = *(const short8*)(WpnT + (nr + l15) * 64 + 32 + l4 * 8);
        f32x4 bb = *(const f32x4*)(b + nr + l4 * 4);
        const int ochunk = (nr >> 3) + (l4 >> 1), obyte = (l4 & 1) * 8;
#pragma unroll
        for (int tt = 0; tt < 4; ++tt) {
            short8 b0 = *(const short8*)(lds + swz(tt * 16 + l15, l4, 128));
            short8 b1 = *(const short8*)(lds + swz(tt * 16 + l15, 4 + l4, 128));
            f32x4 acc = {0.f, 0.f, 0.f, 0.f};
            acc = mfma16(A0, b0, acc);
            acc = mfma16(A1, b1, acc);
            u32x2 p;
            p.x = cvtpk(sp(acc[0] + bb[0]), sp(acc[1] + bb[1]));
            p.y = cvtpk(sp(acc[2] + bb[2]), sp(acc[3] + bb[3]));
            *(u32x2*)(lds + 8192 + swz(tt * 16 + l15, ochunk, 128) + obyte) = p;
        }
    }
    __syncthreads();
#pragma unroll
    for (int rr = 0; rr < 2; ++rr) {
        int f = t + 256 * rr;
        int e = f >> 3, c = f & 7;
        int n = n0 + e;
        if (n < N) {
            u32x4 d = *(const u32x4*)(lds + 8192 + swz(e, c, 128));
            *(u32x4*)(vb + (size_t)n * 64 + c * 8) = d;
        }
    }
}

// -------- pre-dense attr + fold u into edge/node layer-0 biases ------------
__global__ void pre_attr_kernel(
    const float* __restrict__ ga, const float* __restrict__ Wpa, const float* __restrict__ bpa,
    const float* __restrict__ eW0, const float* __restrict__ eb0,
    const float* __restrict__ nW0, const float* __restrict__ nb0,
    float* __restrict__ u, float* __restrict__ c0e, float* __restrict__ c0n)
{
    __shared__ float us[64];
    const int t = threadIdx.x;
    if (t < 64) {
        float acc = bpa[t];
        for (int k = 0; k < 64; ++k) acc += ga[k] * Wpa[k * 64 + t];
        float uu = sp(acc);
        us[t] = uu;
        u[t] = uu;
    }
    __syncthreads();
    if (t < 128) {
        float acc = eb0[t];
        for (int k = 0; k < 64; ++k) acc += us[k] * eW0[(192 + k) * 128 + t];
        c0e[t] = acc;
        float accn = nb0[t];
        for (int k = 0; k < 64; ++k) accn += us[k] * nW0[(128 + k) * 128 + t];
        c0n[t] = accn;
    }
}

// ---------------- CSR build ------------------------------------------------
__global__ __launch_bounds__(256) void cnt_kernel(
    const int* __restrict__ dst, int* __restrict__ cnt, int E)
{
    int i = blockIdx.x * 256 + threadIdx.x;
    if (i < E) atomicAdd(&cnt[dst[i]], 1);
}

// block-level exclusive scan: 1024 elems/block
__global__ __launch_bounds__(256) void scan1_kernel(
    const int* __restrict__ cnt, int* __restrict__ woff, int* __restrict__ bsum, int N)
{
    __shared__ int wsum[4];
    const int t = threadIdx.x, lane = t & 63, wv = t >> 6;
    const int i0 = blockIdx.x * 1024 + t * 4;
    int v0 = (i0 + 0 < N) ? cnt[i0 + 0] : 0;
    int v1 = (i0 + 1 < N) ? cnt[i0 + 1] : 0;
    int v2 = (i0 + 2 < N) ? cnt[i0 + 2] : 0;
    int v3 = (i0 + 3 < N) ? cnt[i0 + 3] : 0;
    int ts = v0 + v1 + v2 + v3;
    int sc = ts;
    for (int d = 1; d < 64; d <<= 1) {
        int up = __shfl_up(sc, d);
        if (lane >= d) sc += up;
    }
    if (lane == 63) wsum[wv] = sc;
    __syncthreads();
    int woffs = 0;
    for (int i = 0; i < wv; ++i) woffs += wsum[i];
    int ex = woffs + sc - ts;
    if (i0 + 0 < N) woff[i0 + 0] = ex;            ex += v0;
    if (i0 + 1 < N) woff[i0 + 1] = ex;            ex += v1;
    if (i0 + 2 < N) woff[i0 + 2] = ex;            ex += v2;
    if (i0 + 3 < N) woff[i0 + 3] = ex;
    if (t == 0) bsum[blockIdx.x] = wsum[0] + wsum[1] + wsum[2] + wsum[3];
}

__global__ void scan2_kernel(int* __restrict__ bsum, int nb)
{
    __shared__ int s[256];
    const int t = threadIdx.x;
    if (t < nb) s[t] = bsum[t];
    __syncthreads();
    if (t == 0) {
        int a = 0;
        for (int i = 0; i < nb; ++i) { int v = s[i]; s[i] = a; a += v; }
    }
    __syncthreads();
    if (t < nb) bsum[t] = s[t];
}

__global__ __launch_bounds__(256) void scan3_kernel(
    int* __restrict__ woff, int* __restrict__ wcur, const int* __restrict__ bsum, int N)
{
    const int base = blockIdx.x * 1024;
    const int add = bsum[blockIdx.x];
#pragma unroll
    for (int r = 0; r < 4; ++r) {
        int i = base + r * 256 + threadIdx.x;
        if (i < N) {
            int o = woff[i] + add;
            woff[i] = o;
            wcur[i] = o;
        }
    }
}

__global__ __launch_bounds__(256) void scatter_kernel(
    const int* __restrict__ dst, int* __restrict__ wcur, int* __restrict__ eidx, int E)
{
    int i = blockIdx.x * 256 + threadIdx.x;
    if (i < E) {
        int d = dst[i];
        int p = atomicAdd(&wcur[d], 1);
        eidx[p] = i;
    }
}

// ---------------- edge kernel: 32 edges / block, 4 waves, MFMA -------------
// LDS: X [32][192] bf16 s384 @0 (12288) | H0 [32][128] bf16 s256 @12288 (8192)
//      EF [32][64] bf16 s128 @20480 (4096)  -> 24576 total (6 blocks/CU)
#define ELDS_X  0
#define ELDS_H  12288
#define ELDS_EF 20480

__global__ __launch_bounds__(256, 6) void edge_kernel(
    const float* __restrict__ ef, const unsigned short* __restrict__ vb,
    const int* __restrict__ src, const int* __restrict__ dst,
    const unsigned short* __restrict__ WpeT, const float* __restrict__ bpe,
    const unsigned short* __restrict__ W0T, const float* __restrict__ c0e,
    const unsigned short* __restrict__ W1T, const float* __restrict__ b1,
    const unsigned short* __restrict__ W2T, const float* __restrict__ b2,
    float* __restrict__ e_out, unsigned short* __restrict__ ebf)
{
    __shared__ __align__(16) char lds[24576];
    const int t = threadIdx.x;
    const int w = t >> 6, l = t & 63;
    const int l15 = l & 15, l4 = l >> 4;
    const int e0 = blockIdx.x * 32;

    // phase 0a: edge features fp32 -> bf16 LDS (32 rows x 8 chunks)
    {
        int e = t >> 3, c = t & 7;
        const float* p = ef + (size_t)(e0 + e) * 64 + c * 8;
        f32x4 x0 = *(const f32x4*)p, x1 = *(const f32x4*)(p + 4);
        *(u32x4*)(lds + ELDS_EF + swz(e, c, 128)) = pack8(x0, x1);
    }
    // phase 0b: gather v[src], v[dst] (bf16): 32 rows x 16 chunks
#pragma unroll
    for (int rr = 0; rr < 2; ++rr) {
        int f = t + 256 * rr;
        int e = f >> 4, c = f & 15;
        int node = (c < 8) ? src[e0 + e] : dst[e0 + e];
        u32x4 d = *(const u32x4*)(vb + (size_t)node * 64 + (c & 7) * 8);
        *(u32x4*)(lds + ELDS_X + swz(e, c, 384)) = d;
    }
    __syncthreads();

    // phase 1: pre-dense edge MLP (K=64, N=64) -> X cols 128..191
    {
        const int nr = w * 16;
        short8 A0 = *(const short8*)(WpeT + (nr + l15) * 64 + l4 * 8);
        short8 A1 = *(const short8*)(WpeT + (nr + l15) * 64 + 32 + l4 * 8);
        f32x4 bb = *(const f32x4*)(bpe + nr + l4 * 4);
        const int ochunk = ((128 + nr) >> 3) + (l4 >> 1), obyte = (l4 & 1) * 8;
#pragma unroll
        for (int tt = 0; tt < 2; ++tt) {
            short8 b0 = *(const short8*)(lds + ELDS_EF + swz(tt * 16 + l15, l4, 128));
            short8 b1 = *(const short8*)(lds + ELDS_EF + swz(tt * 16 + l15, 4 + l4, 128));
            f32x4 acc = {0.f, 0.f, 0.f, 0.f};
            acc = mfma16(A0, b0, acc);
            acc = mfma16(A1, b1, acc);
            u32x2 p;
            p.x = cvtpk(sp(acc[0] + bb[0]), sp(acc[1] + bb[1]));
            p.y = cvtpk(sp(acc[2] + bb[2]), sp(acc[3] + bb[3]));
            *(u32x2*)(lds + ELDS_X + swz(tt * 16 + l15, ochunk, 384) + obyte) = p;
        }
    }
    __syncthreads();

    // phase 2: layer0 (K=192, N=128) -> H0
    {
        const int nr0 = w * 32, nr1 = nr0 + 16;
        short8 A[2][6];
#pragma unroll
        for (int a = 0; a < 2; ++a)
#pragma unroll
            for (int ks = 0; ks < 6; ++ks)
                A[a][ks] = *(const short8*)(W0T + (nr0 + a * 16 + l15) * 192 + ks * 32 + l4 * 8);
        f32x4 bb0 = *(const f32x4*)(c0e + nr0 + l4 * 4);
        f32x4 bb1 = *(const f32x4*)(c0e + nr1 + l4 * 4);
        const int oc0 = (nr0 >> 3) + (l4 >> 1), oc1 = (nr1 >> 3) + (l4 >> 1);
        const int obyte = (l4 & 1) * 8;
#pragma unroll
        for (int tt = 0; tt < 2; ++tt) {
            f32x4 a0 = {0.f, 0.f, 0.f, 0.f}, a1 = {0.f, 0.f, 0.f, 0.f};
#pragma unroll
            for (int ks = 0; ks < 6; ++ks) {
                short8 b = *(const short8*)(lds + ELDS_X + swz(tt * 16 + l15, ks * 4 + l4, 384));
                a0 = mfma16(A[0][ks], b, a0);
                a1 = mfma16(A[1][ks], b, a1);
            }
            u32x2 p0, p1;
            p0.x = cvtpk(sp(a0[0] + bb0[0]), sp(a0[1] + bb0[1]));
            p0.y = cvtpk(sp(a0[2] + bb0[2]), sp(a0[3] + bb0[3]));
            p1.x = cvtpk(sp(a1[0] + bb1[0]), sp(a1[1] + bb1[1]));
            p1.y = cvtpk(sp(a1[2] + bb1[2]), sp(a1[3] + bb1[3]));
            *(u32x2*)(lds + ELDS_H + swz(tt * 16 + l15, oc0, 256) + obyte) = p0;
            *(u32x2*)(lds + ELDS_H + swz(tt * 16 + l15, oc1, 256) + obyte) = p1;
        }
    }
    __syncthreads();

    // phase 3: layer1 (K=128, N=128): H0 -> H1 (X region, s256)
    {
        const int nr0 = w * 32, nr1 = nr0 + 16;
        short8 A[2][4];
#pragma unroll
        for (int a = 0; a < 2; ++a)
#pragma unroll
            for (int ks = 0; ks < 4; ++ks)
                A[a][ks] = *(const short8*)(W1T + (nr0 + a * 16 + l15) * 128 + ks * 32 + l4 * 8);
        f32x4 bb0 = *(const f32x4*)(b1 + nr0 + l4 * 4);
        f32x4 bb1 = *(const f32x4*)(b1 + nr1 + l4 * 4);
        const int oc0 = (nr0 >> 3) + (l4 >> 1), oc1 = (nr1 >> 3) + (l4 >> 1);
        const int obyte = (l4 & 1) * 8;
#pragma unroll
        for (int tt = 0; tt < 2; ++tt) {
            f32x4 a0 = {0.f, 0.f, 0.f, 0.f}, a1 = {0.f, 0.f, 0.f, 0.f};
#pragma unroll
            for (int ks = 0; ks < 4; ++ks) {
                short8 b = *(const short8*)(lds + ELDS_H + swz(tt * 16 + l15, ks * 4 + l4, 256));
                a0 = mfma16(A[0][ks], b, a0);
                a1 = mfma16(A[1][ks], b, a1);
            }
            u32x2 p0, p1;
            p0.x = cvtpk(sp(a0[0] + bb0[0]), sp(a0[1] + bb0[1]));
            p0.y = cvtpk(sp(a0[2] + bb0[2]), sp(a0[3] + bb0[3]));
            p1.x = cvtpk(sp(a1[0] + bb1[0]), sp(a1[1] + bb1[1]));
            p1.y = cvtpk(sp(a1[2] + bb1[2]), sp(a1[3] + bb1[3]));
            *(u32x2*)(lds + ELDS_X + swz(tt * 16 + l15, oc0, 256) + obyte) = p0;
            *(u32x2*)(lds + ELDS_X + swz(tt * 16 + l15, oc1, 256) + obyte) = p1;
        }
    }
    __syncthreads();

    // phase 4: layer2 (K=128, N=64): H1 -> e_new (f32, H0 region)
    {
        const int nr = w * 16;
        short8 A[4];
#pragma unroll
        for (int ks = 0; ks < 4; ++ks)
            A[ks] = *(const short8*)(W2T + (nr + l15) * 128 + ks * 32 + l4 * 8);
        f32x4 bb = *(const f32x4*)(b2 + nr + l4 * 4);
        const int ochunk = (nr >> 2) + l4;
#pragma unroll
        for (int tt = 0; tt < 2; ++tt) {
            f32x4 acc = {0.f, 0.f, 0.f, 0.f};
#pragma unroll
            for (int ks = 0; ks < 4; ++ks) {
                short8 b = *(const short8*)(lds + ELDS_X + swz(tt * 16 + l15, ks * 4 + l4, 256));
                acc = mfma16(A[ks], b, acc);
            }
            f32x4 y = {sp(acc[0] + bb[0]), sp(acc[1] + bb[1]),
                       sp(acc[2] + bb[2]), sp(acc[3] + bb[3])};
            *(f32x4*)(lds + ELDS_H + swz(tt * 16 + l15, ochunk, 256)) = y;
        }
    }
    __syncthreads();

    // phase 5: epilogue — skip add + f32 store + bf16 e_new store
#pragma unroll
    for (int rr = 0; rr < 2; ++rr) {
        int f = t + 256 * rr;
        int e = f >> 4, c = f & 15;
        f32x4 en = *(const f32x4*)(lds + ELDS_H + swz(e, c, 256));
        f32x4 ei = *(const f32x4*)(ef + (size_t)(e0 + e) * 64 + c * 4);
        f32x4 o = en + ei;
        *(f32x4*)(e_out + (size_t)(e0 + e) * 64 + c * 4) = o;
        if (ebf) {
            u32x2 pk;
            pk.x = cvtpk(en[0], en[1]);
            pk.y = cvtpk(en[2], en[3]);
            *(u32x2*)(ebf + (size_t)(e0 + e) * 64 + c * 4) = pk;
        }
    }
}

// ---------------- node kernel: 64 nodes / block, CSR gather + MFMA ---------
// LDS: Xn [64][128] bf16 s256 @0 (16384) | H [64][128] bf16 s256 @16384 (16384)
#define NLDS_X 0
#define NLDS_H 16384

__global__ __launch_bounds__(256, 3) void node_kernel(
    const float* __restrict__ nf, const unsigned short* __restrict__ vb,
    const int* __restrict__ cnt, const int* __restrict__ woff,
    const int* __restrict__ eidx,
    const unsigned short* __restrict__ ebf,          // bf16 e_new (or null)
    const float* __restrict__ e_out_full, const float* __restrict__ ef_full,
    const unsigned short* __restrict__ W0T, const float* __restrict__ c0n,
    const unsigned short* __restrict__ W1T, const float* __restrict__ b1,
    const unsigned short* __restrict__ W2T, const float* __restrict__ b2,
    float* __restrict__ v_out, float* __restrict__ acc_e, float* __restrict__ acc_v,
    int N)
{
    __shared__ __align__(16) char lds[32768];
    const int t = threadIdx.x;
    const int w = t >> 6, l = t & 63;
    const int l15 = l & 15, l4 = l >> 4;
    const int n0 = blockIdx.x * 64;

    // phase 0a: v (bf16) rows -> Xn cols 0..63
#pragma unroll
    for (int rr = 0; rr < 2; ++rr) {
        int f = t + 256 * rr;
        int e = f >> 3, c = f & 7;
        int n = n0 + e; if (n >= N) n = N - 1;
        u32x4 d = *(const u32x4*)(vb + (size_t)n * 64 + c * 8);
        *(u32x4*)(lds + NLDS_X + swz(e, c, 256)) = d;
    }
    // phase 0b: CSR gather segment sums. 4 threads per node, 16 cols each.
    {
        const int e = t >> 2, p = t & 3;
        const int n = n0 + e;
        const bool valid = n < N;
        f32x4 a0 = {0,0,0,0}, a1 = {0,0,0,0}, a2 = {0,0,0,0}, a3 = {0,0,0,0};
        float rc = 0.f;
        if (valid) {
            const int off = woff[n], deg = cnt[n];
            rc = 1.f / fmaxf((float)deg, 1.f);
            if (ebf) {
                for (int j = 0; j < deg; ++j) {
                    int ed = eidx[off + j];
                    const unsigned short* row = ebf + (size_t)ed * 64 + p * 16;
                    u32x4 qa = *(const u32x4*)row;
                    u32x4 qb = *(const u32x4*)(row + 8);
                    a0[0] += bflo(qa.x); a0[1] += bfhi(qa.x);
                    a0[2] += bflo(qa.y); a0[3] += bfhi(qa.y);
                    a1[0] += bflo(qa.z); a1[1] += bfhi(qa.z);
                    a1[2] += bflo(qa.w); a1[3] += bfhi(qa.w);
                    a2[0] += bflo(qb.x); a2[1] += bfhi(qb.x);
                    a2[2] += bflo(qb.y); a2[3] += bfhi(qb.y);
                    a3[0] += bflo(qb.z); a3[1] += bfhi(qb.z);
                    a3[2] += bflo(qb.w); a3[3] += bfhi(qb.w);
                }
            } else {
                for (int j = 0; j < deg; ++j) {
                    int ed = eidx[off + j];
                    const float* ro = e_out_full + (size_t)ed * 64 + p * 16;
                    const float* ri = ef_full + (size_t)ed * 64 + p * 16;
                    a0 += *(const f32x4*)(ro + 0)  - *(const f32x4*)(ri + 0);
                    a1 += *(const f32x4*)(ro + 4)  - *(const f32x4*)(ri + 4);
                    a2 += *(const f32x4*)(ro + 8)  - *(const f32x4*)(ri + 8);
                    a3 += *(const f32x4*)(ro + 12) - *(const f32x4*)(ri + 12);
                }
            }
        }
        // raw sums -> H region f32 (for acc_e readout)
        *(f32x4*)(lds + NLDS_H + swz(e, p * 4 + 0, 256)) = a0;
        *(f32x4*)(lds + NLDS_H + swz(e, p * 4 + 1, 256)) = a1;
        *(f32x4*)(lds + NLDS_H + swz(e, p * 4 + 2, 256)) = a2;
        *(f32x4*)(lds + NLDS_H + swz(e, p * 4 + 3, 256)) = a3;
        // ve = mean -> Xn cols 64..127 (bf16)
        *(u32x4*)(lds + NLDS_X + swz(e, 8 + 2 * p, 256)) = pack8(a0 * rc, a1 * rc);
        *(u32x4*)(lds + NLDS_X + swz(e, 9 + 2 * p, 256)) = pack8(a2 * rc, a3 * rc);
    }
    __syncthreads();
    // phase 0c: column sums of raw segment sums -> acc_e
    if (t < 64) {
        float s = 0.f;
        for (int row = 0; row < 64; ++row)
            s += *(const float*)(lds + NLDS_H + swz(row, t >> 2, 256) + (t & 3) * 4);
        atomicAdd(acc_e + t, s);
    }
    __syncthreads();

    // layer0 (K=128, N=128): Xn -> H
    {
        const int nr0 = w * 32, nr1 = nr0 + 16;
        short8 A[2][4];
#pragma unroll
        for (int a = 0; a < 2; ++a)
#pragma unroll
            for (int ks = 0; ks < 4; ++ks)
                A[a][ks] = *(const short8*)(W0T + (nr0 + a * 16 + l15) * 128 + ks * 32 + l4 * 8);
        f32x4 bb0 = *(const f32x4*)(c0n + nr0 + l4 * 4);
        f32x4 bb1 = *(const f32x4*)(c0n + nr1 + l4 * 4);
        const int oc0 = (nr0 >> 3) + (l4 >> 1), oc1 = (nr1 >> 3) + (l4 >> 1);
        const int obyte = (l4 & 1) * 8;
#pragma unroll
        for (int tt = 0; tt < 4; ++tt) {
            f32x4 a0 = {0.f, 0.f, 0.f, 0.f}, a1 = {0.f, 0.f, 0.f, 0.f};
#pragma unroll
            for (int ks = 0; ks < 4; ++ks) {
                short8 b = *(const short8*)(lds + NLDS_X + swz(tt * 16 + l15, ks * 4 + l4, 256));
                a0 = mfma16(A[0][ks], b, a0);
                a1 = mfma16(A[1][ks], b, a1);
            }
            u32x2 p0, p1;
            p0.x = cvtpk(sp(a0[0] + bb0[0]), sp(a0[1] + bb0[1]));
            p0.y = cvtpk(sp(a0[2] + bb0[2]), sp(a0[3] + bb0[3]));
            p1.x = cvtpk(sp(a1[0] + bb1[0]), sp(a1[1] + bb1[1]));
            p1.y = cvtpk(sp(a1[2] + bb1[2]), sp(a1[3] + bb1[3]));
            *(u32x2*)(lds + NLDS_H + swz(tt * 16 + l15, oc0, 256) + obyte) = p0;
            *(u32x2*)(lds + NLDS_H + swz(tt * 16 + l15, oc1, 256) + obyte) = p1;
        }
    }
    __syncthreads();

    // layer1 (K=128, N=128): H -> H1 (Xn region)
    {
        const int nr0 = w * 32, nr1 = nr0 + 16;
        short8 A[2][4];
#pragma unroll
        for (int a = 0; a < 2; ++a)
#pragma unroll
            for (int ks = 0; ks < 4; ++ks)
                A[a][ks] = *(const short8*)(W1T + (nr0 + a * 16 + l15) * 128 + ks * 32 + l4 * 8);
        f32x4 bb0 = *(const f32x4*)(b1 + nr0 + l4 * 4);
        f32x4 bb1 = *(const f32x4*)(b1 + nr1 + l4 * 4);
        const int oc0 = (nr0 >> 3) + (l4 >> 1), oc1 = (nr1 >> 3) + (l4 >> 1);
        const int obyte = (l4 & 1) * 8;
#pragma unroll
        for (int tt = 0; tt < 4; ++tt) {
            f32x4 a0 = {0.f, 0.f, 0.f, 0.f}, a1 = {0.f, 0.f, 0.f, 0.f};
#pragma unroll
            for (int ks = 0; ks < 4; ++ks) {
                short8 b = *(const short8*)(lds + NLDS_H + swz(tt * 16 + l15, ks * 4 + l4, 256));
                a0 = mfma16(A[0][ks], b, a0);
                a1 = mfma16(A[1][ks], b, a1);
            }
            u32x2 p0, p1;
            p0.x = cvtpk(sp(a0[0] + bb0[0]), sp(a0[1] + bb0[1]));
            p0.y = cvtpk(sp(a0[2] + bb0[2]), sp(a0[3] + bb0[3]));
            p1.x = cvtpk(sp(a1[0] + bb1[0]), sp(a1[1] + bb1[1]));
            p1.y = cvtpk(sp(a1[2] + bb1[2]), sp(a1[3] + bb1[3]));
            *(u32x2*)(lds + NLDS_X + swz(tt * 16 + l15, oc0, 256) + obyte) = p0;
            *(u32x2*)(lds + NLDS_X + swz(tt * 16 + l15, oc1, 256) + obyte) = p1;
        }
    }
    __syncthreads();

    // layer2 (K=128, N=64): H1 -> v_new (f32, H region; zero invalid cols)
    {
        const int nr = w * 16;
        short8 A[4];
#pragma unroll
        for (int ks = 0; ks < 4; ++ks)
            A[ks] = *(const short8*)(W2T + (nr + l15) * 128 + ks * 32 + l4 * 8);
        f32x4 bb = *(const f32x4*)(b2 + nr + l4 * 4);
        const int ochunk = (nr >> 2) + l4;
#pragma unroll
        for (int tt = 0; tt < 4; ++tt) {
            f32x4 acc = {0.f, 0.f, 0.f, 0.f};
#pragma unroll
            for (int ks = 0; ks < 4; ++ks) {
                short8 b = *(const short8*)(lds + NLDS_X + swz(tt * 16 + l15, ks * 4 + l4, 256));
                acc = mfma16(A[ks], b, acc);
            }
            bool valid = (n0 + tt * 16 + l15) < N;
            f32x4 y;
            y[0] = valid ? sp(acc[0] + bb[0]) : 0.f;
            y[1] = valid ? sp(acc[1] + bb[1]) : 0.f;
            y[2] = valid ? sp(acc[2] + bb[2]) : 0.f;
            y[3] = valid ? sp(acc[3] + bb[3]) : 0.f;
            *(f32x4*)(lds + NLDS_H + swz(tt * 16 + l15, ochunk, 256)) = y;
        }
    }
    __syncthreads();

    // epilogue: skip add + store; column sums -> acc_v
#pragma unroll
    for (int rr = 0; rr < 4; ++rr) {
        int f = t + 256 * rr;
        int e = f >> 4, c = f & 15;
        int n = n0 + e;
        if (n < N) {
            f32x4 vn = *(const f32x4*)(lds + NLDS_H + swz(e, c, 256));
            f32x4 x = *(const f32x4*)(nf + (size_t)n * 64 + c * 4);
            f32x4 o = vn + x;
            *(f32x4*)(v_out + (size_t)n * 64 + c * 4) = o;
        }
    }
    if (t < 64) {
        float s = 0.f;
        for (int row = 0; row < 64; ++row)
            s += *(const float*)(lds + NLDS_H + swz(row, t >> 2, 256) + (t & 3) * 4);
        atomicAdd(acc_v + t, s);
    }
}

// ---------------- attr kernel: single block --------------------------------
__global__ void attr_kernel(
    const float* __restrict__ ga, const float* __restrict__ u,
    const float* __restrict__ acc_e, const float* __restrict__ acc_v,
    const float* __restrict__ W0, const float* __restrict__ b0,
    const float* __restrict__ W1, const float* __restrict__ b1,
    const float* __restrict__ W2, const float* __restrict__ b2,
    float* __restrict__ out_u, float Einv, float Ninv)
{
    __shared__ float ain[192];
    __shared__ float h0[128];
    __shared__ float h1[128];
    const int t = threadIdx.x;
    if (t < 64) {
        ain[t] = u[t];
        ain[64 + t] = acc_e[t] * Einv;
        ain[128 + t] = acc_v[t] * Ninv;
    }
    __syncthreads();
    if (t < 128) {
        float a = b0[t];
        for (int k = 0; k < 192; ++k) a += ain[k] * W0[k * 128 + t];
        h0[t] = sp(a);
    }
    __syncthreads();
    if (t < 128) {
        float a = b1[t];
        for (int k = 0; k < 128; ++k) a += h0[k] * W1[k * 128 + t];
        h1[t] = sp(a);
    }
    __syncthreads();
    if (t < 64) {
        float a = b2[t];
        for (int k = 0; k < 128; ++k) a += h1[k] * W2[k * 64 + t];
        out_u[t] = sp(a) + ga[t];
    }
}

// ---------------------------------------------------------------------------
extern "C" void kernel_launch(void* const* d_in, const int* in_sizes, int n_in,
                              void* d_out, int out_size, void* d_ws, size_t ws_size,
                              hipStream_t stream)
{
    const float* edge_feat = (const float*)d_in[0];
    const float* node_feat = (const float*)d_in[1];
    const float* graph_attr = (const float*)d_in[2];
    const int*   src = (const int*)d_in[3];
    const int*   dst = (const int*)d_in[4];
    const float* pre_edge_w = (const float*)d_in[5];
    const float* pre_edge_b = (const float*)d_in[6];
    const float* pre_node_w = (const float*)d_in[7];
    const float* pre_node_b = (const float*)d_in[8];
    const float* pre_attr_w = (const float*)d_in[9];
    const float* pre_attr_b = (const float*)d_in[10];
    const float* edge_w0 = (const float*)d_in[11];
    const float* edge_b0 = (const float*)d_in[12];
    const float* edge_w1 = (const float*)d_in[13];
    const float* edge_b1 = (const float*)d_in[14];
    const float* edge_w2 = (const float*)d_in[15];
    const float* edge_b2 = (const float*)d_in[16];
    const float* node_w0 = (const float*)d_in[17];
    const float* node_b0 = (const float*)d_in[18];
    const float* node_w1 = (const float*)d_in[19];
    const float* node_b1 = (const float*)d_in[20];
    const float* node_w2 = (const float*)d_in[21];
    const float* node_b2 = (const float*)d_in[22];
    const float* attr_w0 = (const float*)d_in[23];
    const float* attr_b0 = (const float*)d_in[24];
    const float* attr_w1 = (const float*)d_in[25];
    const float* attr_b1 = (const float*)d_in[26];
    const float* attr_w2 = (const float*)d_in[27];
    const float* attr_b2 = (const float*)d_in[28];

    const int E = in_sizes[0] / 64;
    const int N = in_sizes[1] / 64;
    const int NB = (N + 1023) / 1024;           // scan blocks

    // workspace layout. acc_e | acc_v | cnt are FIRST and contiguous so one
    // memset of (128 + N) * 4 bytes resets ALL cross-call accumulators.
    char* wsB = (char*)d_ws;
    size_t off = 0;
    auto alloc = [&](size_t bytes) { char* p = wsB + off; off += (bytes + 15) & ~(size_t)15; return p; };
    float* acc_e = (float*)alloc(64 * 4);
    float* acc_v = (float*)alloc(64 * 4);
    int*   cnt   = (int*)alloc((size_t)N * 4);
    float* u     = (float*)alloc(64 * 4);
    float* c0e   = (float*)alloc(128 * 4);
    float* c0n   = (float*)alloc(128 * 4);
    int*   bsum  = (int*)alloc((size_t)NB * 4);
    int*   woff  = (int*)alloc((size_t)N * 4);
    int*   wcur  = (int*)alloc((size_t)N * 4);
    int*   eidx  = (int*)alloc((size_t)E * 4);
    unsigned short* wT = (unsigned short*)alloc((size_t)98304 * 2);
    unsigned short* vb = (unsigned short*)alloc((size_t)N * 64 * 2);
    size_t off_no_ebf = off;
    unsigned short* ebf = (unsigned short*)alloc((size_t)E * 64 * 2);
    const bool use_ebf = (off <= ws_size);
    if (!use_ebf) { ebf = nullptr; off = off_no_ebf; }

    unsigned short* WpeT = wT;
    unsigned short* We0T = wT + 4096;
    unsigned short* We1T = wT + 28672;
    unsigned short* We2T = wT + 45056;
    unsigned short* Wn0T = wT + 53248;
    unsigned short* Wn1T = wT + 69632;
    unsigned short* Wn2T = wT + 86016;
    unsigned short* WpnT = wT + 94208;

    float* e_out = (float*)d_out;                 // E*64
    float* v_out = e_out + (size_t)E * 64;        // N*64
    float* u_out = v_out + (size_t)N * 64;        // 64

    // zero ALL accumulators: acc_e (64f) + acc_v (64f) + cnt (N ints)
    hipMemsetAsync(acc_e, 0, (size_t)(128 + N) * 4, stream);

    wprep<<<384, 256, 0, stream>>>(pre_edge_w, edge_w0, edge_w1, edge_w2,
                                   node_w0, node_w1, node_w2, pre_node_w, wT);
    pre_node_kernel<<<(N + 63) / 64, 256, 0, stream>>>(node_feat, WpnT, pre_node_b, vb, N);
    pre_attr_kernel<<<1, 128, 0, stream>>>(graph_attr, pre_attr_w, pre_attr_b,
                                           edge_w0, edge_b0, node_w0, node_b0,
                                           u, c0e, c0n);
    cnt_kernel<<<(E + 255) / 256, 256, 0, stream>>>(dst, cnt, E);
    scan1_kernel<<<NB, 256, 0, stream>>>(cnt, woff, bsum, N);
    scan2_kernel<<<1, 256, 0, stream>>>(bsum, NB);
    scan3_kernel<<<NB, 256, 0, stream>>>(woff, wcur, bsum, N);
    scatter_kernel<<<(E + 255) / 256, 256, 0, stream>>>(dst, wcur, eidx, E);
    edge_kernel<<<E / 32, 256, 0, stream>>>(
        edge_feat, vb, src, dst,
        WpeT, pre_edge_b, We0T, c0e, We1T, edge_b1, We2T, edge_b2,
        e_out, ebf);
    node_kernel<<<(N + 63) / 64, 256, 0, stream>>>(
        node_feat, vb, cnt, woff, eidx, ebf, e_out, edge_feat,
        Wn0T, c0n, Wn1T, node_b1, Wn2T, node_b2,
        v_out, acc_e, acc_v, N);
    attr_kernel<<<1, 128, 0, stream>>>(
        graph_attr, u, acc_e, acc_v,
        attr_w0, attr_b0, attr_w1, attr_b1, attr_w2, attr_b2,
        u_out, 1.f / (float)E, 1.f / (float)N);
}